// Round 3
// baseline (529.679 us; speedup 1.0000x reference)
//
#include <hip/hip_runtime.h>

#define Bn 4
#define Nn_ 2048
#define Dd 1024
#define Hh 8
#define HDd 64
#define Tt 8192   // Bn*Nn_

typedef short s16x8 __attribute__((ext_vector_type(8)));
typedef float f32x4 __attribute__((ext_vector_type(4)));
typedef float f32x16 __attribute__((ext_vector_type(16)));

__device__ __forceinline__ unsigned short f2bf(float f) {
  unsigned u = __float_as_uint(f);
  return (unsigned short)((u + 0x7fffu + ((u >> 16) & 1u)) >> 16);
}

__device__ __forceinline__ void bf8_to_f(const unsigned short* p, float* o) {
  const uint4 u = *(const uint4*)p;
  o[0] = __uint_as_float(u.x << 16);
  o[1] = __uint_as_float(u.x & 0xffff0000u);
  o[2] = __uint_as_float(u.y << 16);
  o[3] = __uint_as_float(u.y & 0xffff0000u);
  o[4] = __uint_as_float(u.z << 16);
  o[5] = __uint_as_float(u.z & 0xffff0000u);
  o[6] = __uint_as_float(u.w << 16);
  o[7] = __uint_as_float(u.w & 0xffff0000u);
}

__device__ __forceinline__ void gld16(const void* g, void* l) {
  __builtin_amdgcn_global_load_lds(
      (const __attribute__((address_space(1))) unsigned int*)(uintptr_t)g,
      (__attribute__((address_space(3))) unsigned int*)(uintptr_t)l, 16, 0, 0);
}

__device__ __forceinline__ void bar_raw() { asm volatile("s_barrier" ::: "memory"); }

// 32-bit LDS byte address from a flat __shared__ pointer (aperture low bits = offset;
// same truncation convention global_load_lds's as3 destination already relies on).
__device__ __forceinline__ unsigned laddr(const void* p) {
  return (unsigned)(uintptr_t)p;
}

// inline-asm ds_read_b128: invisible to hipcc alias analysis, so outstanding
// global_load_lds writes do NOT force compiler-inserted vmcnt drains (rule #18).
#define DSR(dst, a, imm) \
  asm volatile("ds_read_b128 %0, %1 offset:%2" : "=v"(dst) : "v"(a), "n"(imm))

__device__ __forceinline__ void block_reduce2(float& a, float& b, float* sc) {
#pragma unroll
  for (int off = 32; off > 0; off >>= 1) {
    a += __shfl_down(a, off, 64);
    b += __shfl_down(b, off, 64);
  }
  __syncthreads();
  if ((threadIdx.x & 63) == 0) { int wid = threadIdx.x >> 6; sc[wid] = a; sc[4 + wid] = b; }
  __syncthreads();
  a = sc[0] + sc[1] + sc[2] + sc[3];
  b = sc[4] + sc[5] + sc[6] + sc[7];
}

__device__ __forceinline__ float gelu_f(float u) {
  const float c = 0.7978845608028654f * (u + 0.044715f * u * u * u);
  const float e = __expf(2.0f * c);
  const float th = 1.0f - 2.0f / (1.0f + e);
  return 0.5f * u * (1.0f + th);
}

// ---------- weight convert+transpose: W (KxN f32) -> WT (NxK bf16) ----------
__global__ __launch_bounds__(256) void k_wt(const float* __restrict__ W,
                                            unsigned short* __restrict__ WT, int K, int N) {
  __shared__ float tile[32][33];
  const int n0 = blockIdx.x * 32, k0 = blockIdx.y * 32;
  const int tx = threadIdx.x & 31, ty = threadIdx.x >> 5;  // ty 0..7
#pragma unroll
  for (int i = 0; i < 4; i++) {
    const int kk = ty + i * 8;
    tile[kk][tx] = W[(size_t)(k0 + kk) * N + n0 + tx];
  }
  __syncthreads();
#pragma unroll
  for (int i = 0; i < 4; i++) {
    const int nn = ty + i * 8;
    WT[(size_t)(n0 + nn) * K + k0 + tx] = f2bf(tile[tx][nn]);
  }
}

// ---------- LN1 + potential projection (V, gamma) ----------
__global__ __launch_bounds__(256) void k_ln_pot(
    const float* __restrict__ x, const float* __restrict__ g, const float* __restrict__ bt,
    const float* __restrict__ w_pot, const float* __restrict__ b_pot,
    float* __restrict__ V, float* __restrict__ gam) {
  __shared__ float sc[8];
  const int m = blockIdx.x, t = threadIdx.x;
  const float4 xv = ((const float4*)(x + (size_t)m * Dd))[t];
  float s = xv.x + xv.y + xv.z + xv.w;
  float ss = fmaf(xv.x, xv.x, fmaf(xv.y, xv.y, fmaf(xv.z, xv.z, xv.w * xv.w)));
  block_reduce2(s, ss, sc);
  const float mean = s * (1.0f / Dd);
  const float var = ss * (1.0f / Dd) - mean * mean;
  const float rs = rsqrtf(var + 1e-5f);
  const float4 gv = ((const float4*)g)[t];
  const float4 bv = ((const float4*)bt)[t];
  const float xn0 = (xv.x - mean) * rs * gv.x + bv.x;
  const float xn1 = (xv.y - mean) * rs * gv.y + bv.y;
  const float xn2 = (xv.z - mean) * rs * gv.z + bv.z;
  const float xn3 = (xv.w - mean) * rs * gv.w + bv.w;
  const float4 wp0 = ((const float4*)w_pot)[t * 2];
  const float4 wp1 = ((const float4*)w_pot)[t * 2 + 1];
  float s0 = xn0 * wp0.x + xn1 * wp0.z + xn2 * wp1.x + xn3 * wp1.z;
  float s1 = xn0 * wp0.y + xn1 * wp0.w + xn2 * wp1.y + xn3 * wp1.w;
  block_reduce2(s0, s1, sc);
  if (t == 0) {
    V[m] = s0 + b_pot[0];
    const float p1 = s1 + b_pot[1];
    const float sp = fmaxf(p1, 0.0f) + log1pf(expf(-fabsf(p1)));
    gam[m] = sp + 0.1f;
  }
}

// ---------- parallel continued fraction scan (Mobius matrix scan + replay) ----------
__global__ void k_cf_par(const float* __restrict__ V, const float* __restrict__ gam,
                         float* __restrict__ aRe, float* __restrict__ aIm,
                         float* __restrict__ bRe, float* __restrict__ bIm) {
  const int b = blockIdx.x >> 1, dir = blockIdx.x & 1;
  const int l = threadIdx.x;  // 0..63
  const float* Vb = V + b * Nn_;
  const float* gb = gam + b * Nn_;
  float m[8] = {1.f, 0.f, 0.f, 0.f, 0.f, 0.f, 1.f, 0.f};
#pragma unroll 4
  for (int s = 0; s < 32; s++) {
    const int j = l * 32 + s;
    const int i = dir ? (Nn_ - 1 - j) : j;
    const float dre = Vb[i] + 2.0f, dim = -gb[i];
    const float n00r = dre * m[0] - dim * m[1] - m[4];
    const float n00i = dre * m[1] + dim * m[0] - m[5];
    const float n01r = dre * m[2] - dim * m[3] - m[6];
    const float n01i = dre * m[3] + dim * m[2] - m[7];
    m[4] = m[0]; m[5] = m[1]; m[6] = m[2]; m[7] = m[3];
    m[0] = n00r; m[1] = n00i; m[2] = n01r; m[3] = n01i;
    const float rr = 1.0f / (fabsf(m[0]) + fabsf(m[1]) + fabsf(m[4]) + fabsf(m[5]));
#pragma unroll
    for (int q = 0; q < 8; q++) m[q] *= rr;
  }
#pragma unroll
  for (int off = 1; off < 64; off <<= 1) {
    float p[8];
#pragma unroll
    for (int q = 0; q < 8; q++) p[q] = __shfl_up(m[q], off, 64);
    if (l < off) { p[0] = 1.f; p[1] = 0.f; p[2] = 0.f; p[3] = 0.f;
                   p[4] = 0.f; p[5] = 0.f; p[6] = 1.f; p[7] = 0.f; }
    float c[8];
    c[0] = m[0] * p[0] - m[1] * p[1] + m[2] * p[4] - m[3] * p[5];
    c[1] = m[0] * p[1] + m[1] * p[0] + m[2] * p[5] + m[3] * p[4];
    c[2] = m[0] * p[2] - m[1] * p[3] + m[2] * p[6] - m[3] * p[7];
    c[3] = m[0] * p[3] + m[1] * p[2] + m[2] * p[7] + m[3] * p[6];
    c[4] = m[4] * p[0] - m[5] * p[1] + m[6] * p[4] - m[7] * p[5];
    c[5] = m[4] * p[1] + m[5] * p[0] + m[6] * p[5] + m[7] * p[4];
    c[6] = m[4] * p[2] - m[5] * p[3] + m[6] * p[6] - m[7] * p[7];
    c[7] = m[4] * p[3] + m[5] * p[2] + m[6] * p[7] + m[7] * p[6];
    const float rr = 1.0f / (fabsf(c[0]) + fabsf(c[1]) + fabsf(c[4]) + fabsf(c[5]));
#pragma unroll
    for (int q = 0; q < 8; q++) m[q] = c[q] * rr;
  }
  float e[8];
#pragma unroll
  for (int q = 0; q < 8; q++) e[q] = __shfl_up(m[q], 1, 64);
  if (l == 0) { e[0] = 1.f; e[1] = 0.f; e[4] = 0.f; e[5] = 0.f; }
  const float inr = 1.0f / (e[0] * e[0] + e[1] * e[1]);
  float pr = (e[4] * e[0] + e[5] * e[1]) * inr;
  float pi = (e[5] * e[0] - e[4] * e[1]) * inr;
  float* oR = dir ? bRe : aRe;
  float* oI = dir ? bIm : aIm;
#pragma unroll 4
  for (int s = 0; s < 32; s++) {
    const int j = l * 32 + s;
    const int i = dir ? (Nn_ - 1 - j) : j;
    const float dre = Vb[i] + 2.0f, dim = -gb[i];
    const float ar = dre - pr, ai = dim - pi;
    oR[b * Nn_ + i] = ar; oI[b * Nn_ + i] = ai;
    const float r = 1.0f / (ar * ar + ai * ai);
    pr = ar * r; pi = -ai * r;
  }
}

// ---------- x1 = x + [G.re,G.im] @ w_bk + b_bk ----------
__global__ __launch_bounds__(256) void k_bk_add(
    const float* __restrict__ x, const float* __restrict__ aRe, const float* __restrict__ aIm,
    const float* __restrict__ bRe, const float* __restrict__ bIm,
    const float* __restrict__ V, const float* __restrict__ gam,
    const float* __restrict__ w_bk, const float* __restrict__ b_bk, float* __restrict__ x1) {
  const int m = blockIdx.x, t = threadIdx.x;
  const float dre = V[m] + 2.0f, dim = -gam[m];
  const float nr = aRe[m] + bRe[m] - dre;
  const float ni = aIm[m] + bIm[m] - dim;
  const float r = 1.0f / (nr * nr + ni * ni);
  const float Gre = nr * r, Gim = -ni * r;
  const float4 xv = ((const float4*)(x + (size_t)m * Dd))[t];
  const float4 w0 = ((const float4*)w_bk)[t];
  const float4 w1 = ((const float4*)(w_bk + Dd))[t];
  const float4 bb = ((const float4*)b_bk)[t];
  float4 o;
  o.x = xv.x + Gre * w0.x + Gim * w1.x + bb.x;
  o.y = xv.y + Gre * w0.y + Gim * w1.y + bb.y;
  o.z = xv.z + Gre * w0.z + Gim * w1.z + bb.z;
  o.w = xv.w + Gre * w0.w + Gim * w1.w + bb.w;
  ((float4*)(x1 + (size_t)m * Dd))[t] = o;
}

// ---------- layernorm -> bf16 output ----------
__global__ __launch_bounds__(256) void k_ln_bf(
    const float* __restrict__ x, const float* __restrict__ g, const float* __restrict__ bt,
    unsigned short* __restrict__ y) {
  __shared__ float sc[8];
  const int m = blockIdx.x, t = threadIdx.x;
  const float4 xv = ((const float4*)(x + (size_t)m * Dd))[t];
  float s = xv.x + xv.y + xv.z + xv.w;
  float ss = fmaf(xv.x, xv.x, fmaf(xv.y, xv.y, fmaf(xv.z, xv.z, xv.w * xv.w)));
  block_reduce2(s, ss, sc);
  const float mean = s * (1.0f / Dd);
  const float var = ss * (1.0f / Dd) - mean * mean;
  const float rs = rsqrtf(var + 1e-5f);
  const float4 gv = ((const float4*)g)[t];
  const float4 bv = ((const float4*)bt)[t];
  ushort4 pk;
  pk.x = f2bf((xv.x - mean) * rs * gv.x + bv.x);
  pk.y = f2bf((xv.y - mean) * rs * gv.y + bv.y);
  pk.z = f2bf((xv.z - mean) * rs * gv.z + bv.z);
  pk.w = f2bf((xv.w - mean) * rs * gv.w + bv.w);
  ((ushort4*)(y + (size_t)m * Dd))[t] = pk;
}

// ---------- bf16 MFMA GEMM: 256x256 tile, BK=64, 8 waves, 8-phase counted-vmcnt ----------
// ds_read via inline asm (invisible to alias analysis) so the counted vmcnt(6) really
// leaves loads in flight across barriers; lgkmcnt(0)+sched_barrier(0) per rule #18.
#define ISS_H0(sig, slot) { gld16(gA0 + (size_t)(sig) * 32, lA0 + (slot) * 8192); \
                            gld16(gB0 + (size_t)(sig) * 32, lB0 + (slot) * 8192); }
#define ISS_H1(sig, slot) { gld16(gA1 + (size_t)(sig) * 32, lA1 + (slot) * 8192); \
                            gld16(gB1 + (size_t)(sig) * 32, lB1 + (slot) * 8192); }
#define WV6 asm volatile("s_waitcnt vmcnt(6)" ::: "memory")
#define WV4 asm volatile("s_waitcnt vmcnt(4)" ::: "memory")
#define WV3 asm volatile("s_waitcnt vmcnt(3)" ::: "memory")
#define WV0 asm volatile("s_waitcnt vmcnt(0)" ::: "memory")
#define LGKM0 asm volatile("s_waitcnt lgkmcnt(0)" ::: "memory")
#define PHASE(slot, u, ISSUE, WAIT) {                                        \
    const unsigned cb_ = chB[u];                                             \
    s16x8 aF0, aF1, aF2, aF3, bF0, bF1;                                      \
    DSR(aF0, aB0 + cb_, (slot) * 16384);                                     \
    DSR(aF1, aB1 + cb_, (slot) * 16384);                                     \
    DSR(aF2, aB2 + cb_, (slot) * 16384);                                     \
    DSR(aF3, aB3 + cb_, (slot) * 16384);                                     \
    DSR(bF0, bB0 + cb_, (slot) * 16384);                                     \
    DSR(bF1, bB1 + cb_, (slot) * 16384);                                     \
    ISSUE;                                                                   \
    bar_raw();                                                               \
    LGKM0;                                                                   \
    __builtin_amdgcn_sched_barrier(0);                                       \
    __builtin_amdgcn_s_setprio(1);                                           \
    acc[0][0] = __builtin_amdgcn_mfma_f32_32x32x16_bf16(aF0, bF0, acc[0][0], 0, 0, 0); \
    acc[0][1] = __builtin_amdgcn_mfma_f32_32x32x16_bf16(aF0, bF1, acc[0][1], 0, 0, 0); \
    acc[1][0] = __builtin_amdgcn_mfma_f32_32x32x16_bf16(aF1, bF0, acc[1][0], 0, 0, 0); \
    acc[1][1] = __builtin_amdgcn_mfma_f32_32x32x16_bf16(aF1, bF1, acc[1][1], 0, 0, 0); \
    acc[2][0] = __builtin_amdgcn_mfma_f32_32x32x16_bf16(aF2, bF0, acc[2][0], 0, 0, 0); \
    acc[2][1] = __builtin_amdgcn_mfma_f32_32x32x16_bf16(aF2, bF1, acc[2][1], 0, 0, 0); \
    acc[3][0] = __builtin_amdgcn_mfma_f32_32x32x16_bf16(aF3, bF0, acc[3][0], 0, 0, 0); \
    acc[3][1] = __builtin_amdgcn_mfma_f32_32x32x16_bf16(aF3, bF1, acc[3][1], 0, 0, 0); \
    __builtin_amdgcn_s_setprio(0);                                           \
    WAIT;                                                                    \
    bar_raw();                                                               \
  }

__global__ __launch_bounds__(512, 2) void k_gemm8(
    const unsigned short* __restrict__ A, const unsigned short* __restrict__ BT,
    const float* __restrict__ bias, const float* __restrict__ res,
    void* __restrict__ C, int M, int K, int N, int flags, int nb) {
  __shared__ unsigned short As[4 * 256 * 32];  // 64 KB
  __shared__ unsigned short Bs[4 * 256 * 32];  // 64 KB
  (void)M;
  const int t = threadIdx.x;
  const int bid = blockIdx.x;
  const int g = (bid & 7) * (gridDim.x >> 3) + (bid >> 3);  // XCD-aware swizzle (grid%8==0)
  const int n0 = (g % nb) * 256;
  const int m0 = (g / nb) * 256;
  const int lane = t & 63;
  const int w = t >> 6;            // wave 0..7
  const int wm = w >> 2;           // 0..1 -> 128-row half of A-tile
  const int wn = w & 3;            // 0..3 -> 64-col quarter of B-tile
  const int l31 = lane & 31;
  const int ls = lane >> 5;
  const int swz = (lane ^ (lane >> 2)) & 3;  // read-side XOR swizzle (verified 0-conflict)

  const int srow = t >> 2;
  const int gch = ((t & 3) ^ ((srow ^ (srow >> 2)) & 3)) * 8;
  const unsigned short* gA0 = A + (size_t)(m0 + srow) * K + gch;
  const unsigned short* gA1 = A + (size_t)(m0 + srow + 128) * K + gch;
  const unsigned short* gB0 = BT + (size_t)(n0 + srow) * K + gch;
  const unsigned short* gB1 = BT + (size_t)(n0 + srow + 128) * K + gch;
  unsigned short* lA0 = As + t * 8;
  unsigned short* lA1 = As + (t + 512) * 8;
  unsigned short* lB0 = Bs + t * 8;
  unsigned short* lB1 = Bs + (t + 512) * 8;

  // LDS byte addresses for the asm ds_reads (within slot 0; slot adds offset: imm)
  const unsigned chB[2] = { (unsigned)(((0 * 2 + ls) ^ swz) * 16),
                            (unsigned)(((1 * 2 + ls) ^ swz) * 16) };
  const unsigned aB0 = laddr(As) + 2u * (unsigned)((wm * 128 + 0 * 32 + l31) * 32);
  const unsigned aB1 = laddr(As) + 2u * (unsigned)((wm * 128 + 1 * 32 + l31) * 32);
  const unsigned aB2 = laddr(As) + 2u * (unsigned)((wm * 128 + 2 * 32 + l31) * 32);
  const unsigned aB3 = laddr(As) + 2u * (unsigned)((wm * 128 + 3 * 32 + l31) * 32);
  const unsigned bB0 = laddr(Bs) + 2u * (unsigned)((wn * 64 + 0 * 32 + l31) * 32);
  const unsigned bB1 = laddr(Bs) + 2u * (unsigned)((wn * 64 + 1 * 32 + l31) * 32);

  f32x16 acc[4][2];
#pragma unroll
  for (int i = 0; i < 4; i++)
#pragma unroll
    for (int j = 0; j < 2; j++)
#pragma unroll
      for (int q = 0; q < 16; q++) acc[i][j][q] = 0.0f;

  const int NT = K >> 6;  // K-tiles of 64

  ISS_H0(0, 0); ISS_H1(0, 0); ISS_H0(1, 1); ISS_H1(1, 1); ISS_H0(2, 2);
  WV6;
  bar_raw();

  const int MAIN = (NT - 2) >> 1;
  for (int it = 0; it < MAIN; ++it) {
    const int s0 = 4 * it;
    PHASE(0, 0, ISS_H1(s0 + 2, 2), );
    PHASE(0, 1, ISS_H0(s0 + 3, 3), WV6);
    PHASE(1, 0, ISS_H1(s0 + 3, 3), );
    PHASE(1, 1, ISS_H0(s0 + 4, 0), WV6);
    PHASE(2, 0, ISS_H1(s0 + 4, 0), );
    PHASE(2, 1, ISS_H0(s0 + 5, 1), WV6);
    PHASE(3, 0, ISS_H1(s0 + 5, 1), );
    PHASE(3, 1, ISS_H0(s0 + 6, 2), WV6);
  }
  {
    const int e0 = 2 * NT - 4;
    PHASE(0, 0, ISS_H1(e0 + 2, 2), );
    PHASE(0, 1, ISS_H0(e0 + 3, 3), WV6);
    PHASE(1, 0, ISS_H1(e0 + 3, 3), );
    PHASE(1, 1, , WV4);
    PHASE(2, 0, , );
    PHASE(2, 1, , WV0);
    PHASE(3, 0, , );
    PHASE(3, 1, , );
  }

  const int rbase = 4 * ls;
  float bsv[2];
#pragma unroll
  for (int nt = 0; nt < 2; nt++) bsv[nt] = bias[n0 + wn * 64 + nt * 32 + l31];
#pragma unroll
  for (int mt = 0; mt < 4; mt++)
#pragma unroll
    for (int nt = 0; nt < 2; nt++)
#pragma unroll
      for (int reg = 0; reg < 16; reg++) {
        const size_t row = (size_t)(m0 + wm * 128 + mt * 32 + rbase + (reg & 3) + 8 * (reg >> 2));
        const int col = n0 + wn * 64 + nt * 32 + l31;
        float v = acc[mt][nt][reg] + bsv[nt];
        if (flags & 1) v = gelu_f(v);
        if (flags & 2) v += res[row * N + col];
        if (flags & 4) ((unsigned short*)C)[row * N + col] = f2bf(v);
        else ((float*)C)[row * N + col] = v;
      }
}

// ---------- bf16 MFMA GEMM: 128x256 tile, 8 waves, 4-phase/4-slice counted-vmcnt ----------
// (out-proj, ff2: 256 blocks -> full fill). Same asm-ds_read discipline.
#define ISA_N(sig)  gld16(gA  + (size_t)(sig) * 32, lA  + ((sig) & 3) * 4096)
#define ISB0_N(sig) gld16(gB0 + (size_t)(sig) * 32, lB0 + ((sig) & 3) * 8192)
#define ISB1_N(sig) gld16(gB1 + (size_t)(sig) * 32, lB1 + ((sig) & 3) * 8192)
#define TRIO_N(sig) { ISA_N(sig); ISB0_N(sig); ISB1_N(sig); }
#define MFMA_B(a, b, c) __builtin_amdgcn_mfma_f32_32x32x16_bf16(a, b, c, 0, 0, 0)
#define PHASEN(slot, ISSUE, WAIT) {                                         \
    s16x8 a00, a10, b00, b10, a01, a11, b01, b11;                           \
    DSR(a00, aB0 + cb0, (slot) * 8192);                                     \
    DSR(a10, aB1 + cb0, (slot) * 8192);                                     \
    DSR(b00, bB0 + cb0, (slot) * 16384);                                    \
    DSR(b10, bB1 + cb0, (slot) * 16384);                                    \
    DSR(a01, aB0 + cb1, (slot) * 8192);                                     \
    DSR(a11, aB1 + cb1, (slot) * 8192);                                     \
    DSR(b01, bB0 + cb1, (slot) * 16384);                                    \
    DSR(b11, bB1 + cb1, (slot) * 16384);                                    \
    ISSUE;                                                                  \
    bar_raw();                                                              \
    LGKM0;                                                                  \
    __builtin_amdgcn_sched_barrier(0);                                      \
    __builtin_amdgcn_s_setprio(1);                                          \
    acc[0][0] = MFMA_B(a00, b00, acc[0][0]);                                \
    acc[0][1] = MFMA_B(a00, b10, acc[0][1]);                                \
    acc[1][0] = MFMA_B(a10, b00, acc[1][0]);                                \
    acc[1][1] = MFMA_B(a10, b10, acc[1][1]);                                \
    acc[0][0] = MFMA_B(a01, b01, acc[0][0]);                                \
    acc[0][1] = MFMA_B(a01, b11, acc[0][1]);                                \
    acc[1][0] = MFMA_B(a11, b01, acc[1][0]);                                \
    acc[1][1] = MFMA_B(a11, b11, acc[1][1]);                                \
    __builtin_amdgcn_s_setprio(0);                                          \
    WAIT;                                                                   \
    bar_raw();                                                              \
  }

__global__ __launch_bounds__(512, 2) void k_gemm8n(
    const unsigned short* __restrict__ A, const unsigned short* __restrict__ BT,
    const float* __restrict__ bias, const float* __restrict__ res,
    void* __restrict__ C, int M, int K, int N, int flags, int nb) {
  __shared__ unsigned short As[4 * 128 * 32];  // 32 KB
  __shared__ unsigned short Bs[4 * 256 * 32];  // 64 KB
  (void)M;
  const int t = threadIdx.x;
  const int bid = blockIdx.x;
  const int g = (bid & 7) * (gridDim.x >> 3) + (bid >> 3);  // XCD swizzle (grid%8==0)
  const int n0 = (g % nb) * 256;
  const int m0 = (g / nb) * 128;
  const int lane = t & 63;
  const int w = t >> 6;            // wave 0..7
  const int wm = w >> 2;           // 0..1 -> 64-row half of A-tile
  const int wn = w & 3;            // 0..3 -> 64-col quarter of B-tile
  const int l31 = lane & 31;
  const int ls = lane >> 5;
  const int swz = (lane ^ (lane >> 2)) & 3;

  const int srow = t >> 2;  // 0..127
  const int gch = ((t & 3) ^ ((srow ^ (srow >> 2)) & 3)) * 8;
  const unsigned short* gA  = A  + (size_t)(m0 + srow) * K + gch;
  const unsigned short* gB0 = BT + (size_t)(n0 + srow) * K + gch;
  const unsigned short* gB1 = BT + (size_t)(n0 + srow + 128) * K + gch;
  unsigned short* lA  = As + t * 8;
  unsigned short* lB0 = Bs + t * 8;
  unsigned short* lB1 = Bs + (t + 512) * 8;

  const unsigned cb0 = (unsigned)(((0 * 2 + ls) ^ swz) * 16);
  const unsigned cb1 = (unsigned)(((1 * 2 + ls) ^ swz) * 16);
  const unsigned aB0 = laddr(As) + 2u * (unsigned)((wm * 64 + l31) * 32);
  const unsigned aB1 = laddr(As) + 2u * (unsigned)((wm * 64 + 32 + l31) * 32);
  const unsigned bB0 = laddr(Bs) + 2u * (unsigned)((wn * 64 + l31) * 32);
  const unsigned bB1 = laddr(Bs) + 2u * (unsigned)((wn * 64 + 32 + l31) * 32);

  f32x16 acc[2][2];
#pragma unroll
  for (int i = 0; i < 2; i++)
#pragma unroll
    for (int j = 0; j < 2; j++)
#pragma unroll
      for (int q = 0; q < 16; q++) acc[i][j][q] = 0.0f;

  const int L = K >> 5;  // 32-K slices (L%4==0, L>=8)

  TRIO_N(0); TRIO_N(1); TRIO_N(2);
  WV6;
  bar_raw();

  const int NIT = (L >> 2) - 1;
  for (int it = 0; it < NIT; ++it) {
    const int s0 = 4 * it;
    PHASEN(0, TRIO_N(s0 + 3), WV6);
    PHASEN(1, TRIO_N(s0 + 4), WV6);
    PHASEN(2, TRIO_N(s0 + 5), WV6);
    PHASEN(3, TRIO_N(s0 + 6), WV6);
  }
  PHASEN(0, TRIO_N(L - 1), WV6);
  PHASEN(1, , WV3);
  PHASEN(2, , WV0);
  PHASEN(3, , );

  const int rbase = 4 * ls;
  float bsv[2];
#pragma unroll
  for (int nt = 0; nt < 2; nt++) bsv[nt] = bias[n0 + wn * 64 + nt * 32 + l31];
#pragma unroll
  for (int mt = 0; mt < 2; mt++)
#pragma unroll
    for (int nt = 0; nt < 2; nt++)
#pragma unroll
      for (int reg = 0; reg < 16; reg++) {
        const size_t row = (size_t)(m0 + wm * 64 + mt * 32 + rbase + (reg & 3) + 8 * (reg >> 2));
        const int col = n0 + wn * 64 + nt * 32 + l31;
        float v = acc[mt][nt][reg] + bsv[nt];
        if (flags & 1) v = gelu_f(v);
        if (flags & 2) v += res[row * N + col];
        if (flags & 4) ((unsigned short*)C)[row * N + col] = f2bf(v);
        else ((float*)C)[row * N + col] = v;
      }
}

// ---------- Hebbian phase A: per-chunk decayed outer-product sums ----------
__global__ __launch_bounds__(256) void k_heb_chunk(
    const unsigned short* __restrict__ qkv, const float* __restrict__ gam,
    float* __restrict__ U, float* __restrict__ Dc) {
  __shared__ float kw[4096];
  __shared__ float vS[4096];
  __shared__ float cum[64];
  const int bx = blockIdx.x;
  const int c = bx & 31, bh = bx >> 5, b = bh >> 3, h = bh & 7;
  const int t = threadIdx.x;
  const int n0 = c * 64;
  const size_t base = ((size_t)(b * Nn_ + n0)) * 1536 + h * 64;
#pragma unroll
  for (int l = 0; l < 2; l++) {
    const int idx8 = t + 256 * l;
    const int s = idx8 >> 3;
    const int d0 = (idx8 & 7) << 3;
    const size_t gi = base + (size_t)s * 1536 + d0;
    bf8_to_f(qkv + gi + 512, &kw[s * 64 + d0]);
    bf8_to_f(qkv + gi + 1024, &vS[s * 64 + d0]);
  }
  if (t < 64) {
    float val = 0.01f * gam[b * Nn_ + n0 + t];
#pragma unroll
    for (int off = 1; off < 64; off <<= 1) {
      const float o = __shfl_up(val, off, 64);
      if (t >= off) val += o;
    }
    cum[t] = val;
  }
  __syncthreads();
  const float total = cum[63];
#pragma unroll
  for (int l = 0; l < 16; l++) {
    const int idx = t + 256 * l;
    const int s = idx >> 6;
    kw[idx] *= 0.1f * __expf(cum[s] - total);
  }
  __syncthreads();
  const int td = (t & 15) << 2, te = (t >> 4) << 2;
  float acc[4][4];
#pragma unroll
  for (int i = 0; i < 4; i++)
#pragma unroll
    for (int j = 0; j < 4; j++) acc[i][j] = 0.0f;
  for (int s = 0; s < 64; s++) {
    const float4 kk = *(const float4*)&kw[s * 64 + td];
    const float4 vv = *(const float4*)&vS[s * 64 + te];
    const float ka[4] = {kk.x, kk.y, kk.z, kk.w};
    const float va[4] = {vv.x, vv.y, vv.z, vv.w};
#pragma unroll
    for (int i = 0; i < 4; i++)
#pragma unroll
      for (int j = 0; j < 4; j++) acc[i][j] = fmaf(ka[i], va[j], acc[i][j]);
  }
  float* Up = U + (size_t)bx * 4096;
#pragma unroll
  for (int i = 0; i < 4; i++)
#pragma unroll
    for (int j = 0; j < 4; j++) Up[(td + i) * 64 + te + j] = acc[i][j];
  if (t == 0) Dc[bx] = __expf(-total);
}

// ---------- Hebbian phase B: carry W across chunks (one thread per element) ----------
__global__ __launch_bounds__(256) void k_heb_scan(
    const float* __restrict__ U, const float* __restrict__ Dc, float* __restrict__ Win) {
  const int gid = blockIdx.x * 256 + threadIdx.x;   // 0..131071
  const int bh = gid >> 12, el = gid & 4095;
  float w = 0.0f;
#pragma unroll 4
  for (int c = 0; c < 32; c++) {
    const size_t idx = (((size_t)(bh * 32 + c)) << 12) + el;
    Win[idx] = w;
    w = Dc[bh * 32 + c] * w + U[idx];
  }
}

// ---------- Hebbian phase C: intra-chunk causal + inter-chunk q@W_in ----------
__global__ __launch_bounds__(256) void k_heb_out(
    const unsigned short* __restrict__ qkv, const float* __restrict__ gam,
    const float* __restrict__ Win, unsigned short* __restrict__ heb) {
  __shared__ float qS[4096];
  __shared__ float kT[4096];
  __shared__ float vS[4096];
  __shared__ float P[4096];
  const int bx = blockIdx.x;
  const int c = bx & 31, bh = bx >> 5, b = bh >> 3, h = bh & 7;
  const int t = threadIdx.x;
  const int n0 = c * 64;
  const size_t base = ((size_t)(b * Nn_ + n0)) * 1536 + h * 64;
#pragma unroll
  for (int l = 0; l < 2; l++) {
    const int idx8 = t + 256 * l;
    const int s = idx8 >> 3;
    const int d0 = (idx8 & 7) << 3;
    const size_t gi = base + (size_t)s * 1536 + d0;
    bf8_to_f(qkv + gi, &qS[s * 64 + d0]);
    bf8_to_f(qkv + gi + 1024, &vS[s * 64 + d0]);
    float tmp[8];
    bf8_to_f(qkv + gi + 512, tmp);
#pragma unroll
    for (int j = 0; j < 8; j++) kT[(d0 + j) * 64 + s] = tmp[j];
  }
  if (t < 64) {
    float val = 0.01f * gam[b * Nn_ + n0 + t];
#pragma unroll
    for (int off = 1; off < 64; off <<= 1) {
      const float o = __shfl_up(val, off, 64);
      if (t >= off) val += o;
    }
    P[t] = val;
  }
  __syncthreads();
  const int tr = (t >> 4) << 2;
  const int tc = (t & 15) << 2;
  float er[4], es[4];
#pragma unroll
  for (int r = 0; r < 4; r++) er[r] = __expf(-P[tr + r]);
#pragma unroll
  for (int j = 0; j < 4; j++) es[j] = 0.1f * __expf(P[tc + j]);
  __syncthreads();
  float acc[4][4];
#pragma unroll
  for (int i = 0; i < 4; i++)
#pragma unroll
    for (int j = 0; j < 4; j++) acc[i][j] = 0.0f;
  for (int d = 0; d < 64; d++) {
    const float4 kk = *(const float4*)&kT[d * 64 + tc];
    const float ka[4] = {kk.x, kk.y, kk.z, kk.w};
#pragma unroll
    for (int r = 0; r < 4; r++) {
      const float qv = qS[(tr + r) * 64 + d];
#pragma unroll
      for (int j = 0; j < 4; j++) acc[r][j] = fmaf(qv, ka[j], acc[r][j]);
    }
  }
#pragma unroll
  for (int r = 0; r < 4; r++)
#pragma unroll
    for (int j = 0; j < 4; j++) {
      const int tt = tr + r, ssi = tc + j;
      const float wgt = (ssi <= tt) ? er[r] * es[j] : 0.0f;
      P[tt * 64 + ssi] = acc[r][j] * wgt;
    }
  __syncthreads();
  const size_t wb = (size_t)bx * 4096;
#pragma unroll
  for (int l = 0; l < 16; l++) {
    const int idx = t + 256 * l;
    kT[idx] = Win[wb + idx];
  }
  __syncthreads();
  float o1[4][4], o2[4][4];
#pragma unroll
  for (int i = 0; i < 4; i++)
#pragma unroll
    for (int j = 0; j < 4; j++) { o1[i][j] = 0.0f; o2[i][j] = 0.0f; }
  for (int s = 0; s < 64; s++) {
    const float4 vv = *(const float4*)&vS[s * 64 + tc];
    const float4 ww = *(const float4*)&kT[s * 64 + tc];
    const float va[4] = {vv.x, vv.y, vv.z, vv.w};
    const float wa[4] = {ww.x, ww.y, ww.z, ww.w};
#pragma unroll
    for (int r = 0; r < 4; r++) {
      const float pv = P[(tr + r) * 64 + s];
      const float qv = qS[(tr + r) * 64 + s];
#pragma unroll
      for (int j = 0; j < 4; j++) {
        o1[r][j] = fmaf(pv, va[j], o1[r][j]);
        o2[r][j] = fmaf(qv, wa[j], o2[r][j]);
      }
    }
  }
#pragma unroll
  for (int r = 0; r < 4; r++) {
    const int n = n0 + tr + r;
    ushort4 pk;
    pk.x = f2bf(o1[r][0] + er[r] * o2[r][0]);
    pk.y = f2bf(o1[r][1] + er[r] * o2[r][1]);
    pk.z = f2bf(o1[r][2] + er[r] * o2[r][2]);
    pk.w = f2bf(o1[r][3] + er[r] * o2[r][3]);
    *(ushort4*)&heb[((size_t)b * Nn_ + n) * 512 + h * 64 + tc] = pk;
  }
}

extern "C" void kernel_launch(void* const* d_in, const int* in_sizes, int n_in,
                              void* d_out, int out_size, void* d_ws, size_t ws_size,
                              hipStream_t stream) {
  const float* x     = (const float*)d_in[0];
  const float* ln1g  = (const float*)d_in[1];
  const float* ln1b  = (const float*)d_in[2];
  const float* ln2g  = (const float*)d_in[3];
  const float* ln2b  = (const float*)d_in[4];
  const float* ln3g  = (const float*)d_in[5];
  const float* ln3b  = (const float*)d_in[6];
  const float* w_pot = (const float*)d_in[7];
  const float* b_pot = (const float*)d_in[8];
  const float* w_bk  = (const float*)d_in[9];
  const float* b_bk  = (const float*)d_in[10];
  const float* w_qkv = (const float*)d_in[11];
  const float* b_qkv = (const float*)d_in[12];
  const float* w_out = (const float*)d_in[13];
  const float* b_out = (const float*)d_in[14];
  const float* w_ff1 = (const float*)d_in[15];
  const float* b_ff1 = (const float*)d_in[16];
  const float* w_ff2 = (const float*)d_in[17];
  const float* b_ff2 = (const float*)d_in[18];
  float* out = (float*)d_out;
  float* ws = (float*)d_ws;

  // ---- workspace layout (float units), total 34,668,544 floats = 138.7 MB ----
  float* V   = ws;
  float* gam = V + 8192;
  float* aRe = gam + 8192;
  float* aIm = aRe + 8192;
  float* bRe = aIm + 8192;
  float* bIm = bRe + 8192;
  float* Dc  = bIm + 8192;
  float* HID = ws + 65536;             // 16.78M f32 (67.1MB): x1 + qkv early; ff hidden late
  float* x1   = HID;                   // 8.39M f32
  unsigned short* qkvb = (unsigned short*)(HID + 8388608);  // 12.58M shorts
  unsigned short* hid  = (unsigned short*)HID;              // 8192x4096 bf16 (ff phase)
  float* RC   = HID + 16777216;        // 8.39M f32: U+Win, later x2
  float* U    = RC;
  float* Win  = RC + 4194304;
  float* x2   = RC;
  float* RD   = RC + 8388608;          // 4.19M f32: xn2/heb/xn3 (bf16)
  unsigned short* xnb = (unsigned short*)RD;
  unsigned short* heb = (unsigned short*)RD;
  unsigned short* wE  = (unsigned short*)(RD + 4194304);
  unsigned short* wqkvT = wE;                    // 1536x1024
  unsigned short* woutT = wqkvT + 1572864;       // 1024x512
  unsigned short* wff1T = woutT + 524288;        // 4096x1024
  unsigned short* wff2T = wff1T + 4194304;       // 1024x4096

  // weight transposes (fp32 KxN -> bf16 NxK)
  k_wt<<<dim3(1536 / 32, 1024 / 32), 256, 0, stream>>>(w_qkv, wqkvT, 1024, 1536);
  k_wt<<<dim3(1024 / 32, 512 / 32), 256, 0, stream>>>(w_out, woutT, 512, 1024);
  k_wt<<<dim3(4096 / 32, 1024 / 32), 256, 0, stream>>>(w_ff1, wff1T, 1024, 4096);
  k_wt<<<dim3(1024 / 32, 4096 / 32), 256, 0, stream>>>(w_ff2, wff2T, 4096, 1024);

  k_ln_pot<<<Tt, 256, 0, stream>>>(x, ln1g, ln1b, w_pot, b_pot, V, gam);
  k_cf_par<<<8, 64, 0, stream>>>(V, gam, aRe, aIm, bRe, bIm);
  k_bk_add<<<Tt, 256, 0, stream>>>(x, aRe, aIm, bRe, bIm, V, gam, w_bk, b_bk, x1);
  k_ln_bf<<<Tt, 256, 0, stream>>>(x1, ln2g, ln2b, xnb);
  // qkv: (8192x1024)@(1024x1536) -> bf16   [256^2 tile, nb=6, 192 blocks]
  k_gemm8<<<192, 512, 0, stream>>>(xnb, wqkvT, b_qkv, nullptr, qkvb,
                                   8192, 1024, 1536, 4, 6);
  k_heb_chunk<<<1024, 256, 0, stream>>>(qkvb, gam, U, Dc);
  k_heb_scan<<<512, 256, 0, stream>>>(U, Dc, Win);
  k_heb_out<<<1024, 256, 0, stream>>>(qkvb, gam, Win, heb);
  // out-proj: (8192x512)@(512x1024) + x1 -> f32 x2   [128x256 tile, nb=4, 256 blocks]
  k_gemm8n<<<256, 512, 0, stream>>>(heb, woutT, b_out, x1, x2,
                                    8192, 512, 1024, 2, 4);
  k_ln_bf<<<Tt, 256, 0, stream>>>(x2, ln3g, ln3b, xnb);
  // ff1: (8192x1024)@(1024x4096) gelu -> bf16 hid   [256^2 tile, nb=16, 512 blocks]
  k_gemm8<<<512, 512, 0, stream>>>(xnb, wff1T, b_ff1, nullptr, hid,
                                   8192, 1024, 4096, 1 | 4, 16);
  // ff2: (8192x4096)@(4096x1024) + x2 -> f32 out   [128x256 tile, nb=4, 256 blocks]
  k_gemm8n<<<256, 512, 0, stream>>>(hid, wff2T, b_ff2, x2, out,
                                    8192, 4096, 1024, 2, 4);
}

// Round 4
// 517.854 us; speedup vs baseline: 1.0228x; 1.0228x over previous
//
#include <hip/hip_runtime.h>

#define Bn 4
#define Nn_ 2048
#define Dd 1024
#define Hh 8
#define HDd 64
#define Tt 8192   // Bn*Nn_

typedef short s16x8 __attribute__((ext_vector_type(8)));
typedef float f32x4 __attribute__((ext_vector_type(4)));
typedef float f32x16 __attribute__((ext_vector_type(16)));

__device__ __forceinline__ unsigned short f2bf(float f) {
  unsigned u = __float_as_uint(f);
  return (unsigned short)((u + 0x7fffu + ((u >> 16) & 1u)) >> 16);
}

__device__ __forceinline__ void bf8_to_f(const unsigned short* p, float* o) {
  const uint4 u = *(const uint4*)p;
  o[0] = __uint_as_float(u.x << 16);
  o[1] = __uint_as_float(u.x & 0xffff0000u);
  o[2] = __uint_as_float(u.y << 16);
  o[3] = __uint_as_float(u.y & 0xffff0000u);
  o[4] = __uint_as_float(u.z << 16);
  o[5] = __uint_as_float(u.z & 0xffff0000u);
  o[6] = __uint_as_float(u.w << 16);
  o[7] = __uint_as_float(u.w & 0xffff0000u);
}

__device__ __forceinline__ void gld16(const void* g, void* l) {
  __builtin_amdgcn_global_load_lds(
      (const __attribute__((address_space(1))) unsigned int*)(uintptr_t)g,
      (__attribute__((address_space(3))) unsigned int*)(uintptr_t)l, 16, 0, 0);
}

__device__ __forceinline__ void bar_raw() { asm volatile("s_barrier" ::: "memory"); }

__device__ __forceinline__ unsigned laddr(const void* p) {
  return (unsigned)(uintptr_t)p;
}

// inline-asm ds_read_b128 (opaque to alias analysis)
#define DSR(dst, a, imm) \
  asm volatile("ds_read_b128 %0, %1 offset:%2" : "=v"(dst) : "v"(a), "n"(imm))

__device__ __forceinline__ void block_reduce2(float& a, float& b, float* sc) {
#pragma unroll
  for (int off = 32; off > 0; off >>= 1) {
    a += __shfl_down(a, off, 64);
    b += __shfl_down(b, off, 64);
  }
  __syncthreads();
  if ((threadIdx.x & 63) == 0) { int wid = threadIdx.x >> 6; sc[wid] = a; sc[4 + wid] = b; }
  __syncthreads();
  a = sc[0] + sc[1] + sc[2] + sc[3];
  b = sc[4] + sc[5] + sc[6] + sc[7];
}

__device__ __forceinline__ float gelu_f(float u) {
  const float c = 0.7978845608028654f * (u + 0.044715f * u * u * u);
  const float e = __expf(2.0f * c);
  const float th = 1.0f - 2.0f / (1.0f + e);
  return 0.5f * u * (1.0f + th);
}

// ---------- weight convert+transpose: W (KxN f32) -> WT (NxK bf16) ----------
__global__ __launch_bounds__(256) void k_wt(const float* __restrict__ W,
                                            unsigned short* __restrict__ WT, int K, int N) {
  __shared__ float tile[32][33];
  const int n0 = blockIdx.x * 32, k0 = blockIdx.y * 32;
  const int tx = threadIdx.x & 31, ty = threadIdx.x >> 5;  // ty 0..7
#pragma unroll
  for (int i = 0; i < 4; i++) {
    const int kk = ty + i * 8;
    tile[kk][tx] = W[(size_t)(k0 + kk) * N + n0 + tx];
  }
  __syncthreads();
#pragma unroll
  for (int i = 0; i < 4; i++) {
    const int nn = ty + i * 8;
    WT[(size_t)(n0 + nn) * K + k0 + tx] = f2bf(tile[tx][nn]);
  }
}

// ---------- LN1 + potential projection (V, gamma) ----------
__global__ __launch_bounds__(256) void k_ln_pot(
    const float* __restrict__ x, const float* __restrict__ g, const float* __restrict__ bt,
    const float* __restrict__ w_pot, const float* __restrict__ b_pot,
    float* __restrict__ V, float* __restrict__ gam) {
  __shared__ float sc[8];
  const int m = blockIdx.x, t = threadIdx.x;
  const float4 xv = ((const float4*)(x + (size_t)m * Dd))[t];
  float s = xv.x + xv.y + xv.z + xv.w;
  float ss = fmaf(xv.x, xv.x, fmaf(xv.y, xv.y, fmaf(xv.z, xv.z, xv.w * xv.w)));
  block_reduce2(s, ss, sc);
  const float mean = s * (1.0f / Dd);
  const float var = ss * (1.0f / Dd) - mean * mean;
  const float rs = rsqrtf(var + 1e-5f);
  const float4 gv = ((const float4*)g)[t];
  const float4 bv = ((const float4*)bt)[t];
  const float xn0 = (xv.x - mean) * rs * gv.x + bv.x;
  const float xn1 = (xv.y - mean) * rs * gv.y + bv.y;
  const float xn2 = (xv.z - mean) * rs * gv.z + bv.z;
  const float xn3 = (xv.w - mean) * rs * gv.w + bv.w;
  const float4 wp0 = ((const float4*)w_pot)[t * 2];
  const float4 wp1 = ((const float4*)w_pot)[t * 2 + 1];
  float s0 = xn0 * wp0.x + xn1 * wp0.z + xn2 * wp1.x + xn3 * wp1.z;
  float s1 = xn0 * wp0.y + xn1 * wp0.w + xn2 * wp1.y + xn3 * wp1.w;
  block_reduce2(s0, s1, sc);
  if (t == 0) {
    V[m] = s0 + b_pot[0];
    const float p1 = s1 + b_pot[1];
    const float sp = fmaxf(p1, 0.0f) + log1pf(expf(-fabsf(p1)));
    gam[m] = sp + 0.1f;
  }
}

// ---------- parallel continued fraction scan (Mobius matrix scan + replay) ----------
__global__ void k_cf_par(const float* __restrict__ V, const float* __restrict__ gam,
                         float* __restrict__ aRe, float* __restrict__ aIm,
                         float* __restrict__ bRe, float* __restrict__ bIm) {
  const int b = blockIdx.x >> 1, dir = blockIdx.x & 1;
  const int l = threadIdx.x;  // 0..63
  const float* Vb = V + b * Nn_;
  const float* gb = gam + b * Nn_;
  float m[8] = {1.f, 0.f, 0.f, 0.f, 0.f, 0.f, 1.f, 0.f};
#pragma unroll 4
  for (int s = 0; s < 32; s++) {
    const int j = l * 32 + s;
    const int i = dir ? (Nn_ - 1 - j) : j;
    const float dre = Vb[i] + 2.0f, dim = -gb[i];
    const float n00r = dre * m[0] - dim * m[1] - m[4];
    const float n00i = dre * m[1] + dim * m[0] - m[5];
    const float n01r = dre * m[2] - dim * m[3] - m[6];
    const float n01i = dre * m[3] + dim * m[2] - m[7];
    m[4] = m[0]; m[5] = m[1]; m[6] = m[2]; m[7] = m[3];
    m[0] = n00r; m[1] = n00i; m[2] = n01r; m[3] = n01i;
    const float rr = 1.0f / (fabsf(m[0]) + fabsf(m[1]) + fabsf(m[4]) + fabsf(m[5]));
#pragma unroll
    for (int q = 0; q < 8; q++) m[q] *= rr;
  }
#pragma unroll
  for (int off = 1; off < 64; off <<= 1) {
    float p[8];
#pragma unroll
    for (int q = 0; q < 8; q++) p[q] = __shfl_up(m[q], off, 64);
    if (l < off) { p[0] = 1.f; p[1] = 0.f; p[2] = 0.f; p[3] = 0.f;
                   p[4] = 0.f; p[5] = 0.f; p[6] = 1.f; p[7] = 0.f; }
    float c[8];
    c[0] = m[0] * p[0] - m[1] * p[1] + m[2] * p[4] - m[3] * p[5];
    c[1] = m[0] * p[1] + m[1] * p[0] + m[2] * p[5] + m[3] * p[4];
    c[2] = m[0] * p[2] - m[1] * p[3] + m[2] * p[6] - m[3] * p[7];
    c[3] = m[0] * p[3] + m[1] * p[2] + m[2] * p[7] + m[3] * p[6];
    c[4] = m[4] * p[0] - m[5] * p[1] + m[6] * p[4] - m[7] * p[5];
    c[5] = m[4] * p[1] + m[5] * p[0] + m[6] * p[5] + m[7] * p[4];
    c[6] = m[4] * p[2] - m[5] * p[3] + m[6] * p[6] - m[7] * p[7];
    c[7] = m[4] * p[3] + m[5] * p[2] + m[6] * p[7] + m[7] * p[6];
    const float rr = 1.0f / (fabsf(c[0]) + fabsf(c[1]) + fabsf(c[4]) + fabsf(c[5]));
#pragma unroll
    for (int q = 0; q < 8; q++) m[q] = c[q] * rr;
  }
  float e[8];
#pragma unroll
  for (int q = 0; q < 8; q++) e[q] = __shfl_up(m[q], 1, 64);
  if (l == 0) { e[0] = 1.f; e[1] = 0.f; e[4] = 0.f; e[5] = 0.f; }
  const float inr = 1.0f / (e[0] * e[0] + e[1] * e[1]);
  float pr = (e[4] * e[0] + e[5] * e[1]) * inr;
  float pi = (e[5] * e[0] - e[4] * e[1]) * inr;
  float* oR = dir ? bRe : aRe;
  float* oI = dir ? bIm : aIm;
#pragma unroll 4
  for (int s = 0; s < 32; s++) {
    const int j = l * 32 + s;
    const int i = dir ? (Nn_ - 1 - j) : j;
    const float dre = Vb[i] + 2.0f, dim = -gb[i];
    const float ar = dre - pr, ai = dim - pi;
    oR[b * Nn_ + i] = ar; oI[b * Nn_ + i] = ai;
    const float r = 1.0f / (ar * ar + ai * ai);
    pr = ar * r; pi = -ai * r;
  }
}

// ---------- x1 = x + [G.re,G.im] @ w_bk + b_bk ----------
__global__ __launch_bounds__(256) void k_bk_add(
    const float* __restrict__ x, const float* __restrict__ aRe, const float* __restrict__ aIm,
    const float* __restrict__ bRe, const float* __restrict__ bIm,
    const float* __restrict__ V, const float* __restrict__ gam,
    const float* __restrict__ w_bk, const float* __restrict__ b_bk, float* __restrict__ x1) {
  const int m = blockIdx.x, t = threadIdx.x;
  const float dre = V[m] + 2.0f, dim = -gam[m];
  const float nr = aRe[m] + bRe[m] - dre;
  const float ni = aIm[m] + bIm[m] - dim;
  const float r = 1.0f / (nr * nr + ni * ni);
  const float Gre = nr * r, Gim = -ni * r;
  const float4 xv = ((const float4*)(x + (size_t)m * Dd))[t];
  const float4 w0 = ((const float4*)w_bk)[t];
  const float4 w1 = ((const float4*)(w_bk + Dd))[t];
  const float4 bb = ((const float4*)b_bk)[t];
  float4 o;
  o.x = xv.x + Gre * w0.x + Gim * w1.x + bb.x;
  o.y = xv.y + Gre * w0.y + Gim * w1.y + bb.y;
  o.z = xv.z + Gre * w0.z + Gim * w1.z + bb.z;
  o.w = xv.w + Gre * w0.w + Gim * w1.w + bb.w;
  ((float4*)(x1 + (size_t)m * Dd))[t] = o;
}

// ---------- layernorm -> bf16 output ----------
__global__ __launch_bounds__(256) void k_ln_bf(
    const float* __restrict__ x, const float* __restrict__ g, const float* __restrict__ bt,
    unsigned short* __restrict__ y) {
  __shared__ float sc[8];
  const int m = blockIdx.x, t = threadIdx.x;
  const float4 xv = ((const float4*)(x + (size_t)m * Dd))[t];
  float s = xv.x + xv.y + xv.z + xv.w;
  float ss = fmaf(xv.x, xv.x, fmaf(xv.y, xv.y, fmaf(xv.z, xv.z, xv.w * xv.w)));
  block_reduce2(s, ss, sc);
  const float mean = s * (1.0f / Dd);
  const float var = ss * (1.0f / Dd) - mean * mean;
  const float rs = rsqrtf(var + 1e-5f);
  const float4 gv = ((const float4*)g)[t];
  const float4 bv = ((const float4*)bt)[t];
  ushort4 pk;
  pk.x = f2bf((xv.x - mean) * rs * gv.x + bv.x);
  pk.y = f2bf((xv.y - mean) * rs * gv.y + bv.y);
  pk.z = f2bf((xv.z - mean) * rs * gv.z + bv.z);
  pk.w = f2bf((xv.w - mean) * rs * gv.w + bv.w);
  ((ushort4*)(y + (size_t)m * Dd))[t] = pk;
}

// ---------- bf16 MFMA GEMM: 256x256 tile, BK=64, 8 waves ----------
// Register-double-buffered fragments: phase P issues ds_reads for P+1 BEFORE the
// MFMA cluster of P, waits with COUNTED lgkmcnt(6) -> LDS drain hides under MFMA.
// One barrier per phase; per-phase vmcnt(4) (2 half-pairs in flight).
// Ring: slice sigma (32-K) in slot sigma&3; staged ~2.5 slices ahead of consumption.
#define ISS_H0(sig, slot) { gld16(gA0 + (size_t)(sig) * 32, lA0 + (slot) * 8192); \
                            gld16(gB0 + (size_t)(sig) * 32, lB0 + (slot) * 8192); }
#define ISS_H1(sig, slot) { gld16(gA1 + (size_t)(sig) * 32, lA1 + (slot) * 8192); \
                            gld16(gB1 + (size_t)(sig) * 32, lB1 + (slot) * 8192); }
#define WV4 asm volatile("s_waitcnt vmcnt(4)" ::: "memory")
#define WV3 asm volatile("s_waitcnt vmcnt(3)" ::: "memory")
#define WV2 asm volatile("s_waitcnt vmcnt(2)" ::: "memory")
#define WV0 asm volatile("s_waitcnt vmcnt(0)" ::: "memory")
#define LGKM0 asm volatile("s_waitcnt lgkmcnt(0)" ::: "memory")
#define LGKM6 asm volatile("s_waitcnt lgkmcnt(6)" ::: "memory")
#define LGKM8 asm volatile("s_waitcnt lgkmcnt(8)" ::: "memory")
#define MFMA_B(a, b, c) __builtin_amdgcn_mfma_f32_32x32x16_bf16(a, b, c, 0, 0, 0)

#define MM8CLUSTER {                                   \
    __builtin_amdgcn_s_setprio(1);                     \
    acc[0][0] = MFMA_B(cA0, cB0, acc[0][0]);           \
    acc[0][1] = MFMA_B(cA0, cB1, acc[0][1]);           \
    acc[1][0] = MFMA_B(cA1, cB0, acc[1][0]);           \
    acc[1][1] = MFMA_B(cA1, cB1, acc[1][1]);           \
    acc[2][0] = MFMA_B(cA2, cB0, acc[2][0]);           \
    acc[2][1] = MFMA_B(cA2, cB1, acc[2][1]);           \
    acc[3][0] = MFMA_B(cA3, cB0, acc[3][0]);           \
    acc[3][1] = MFMA_B(cA3, cB1, acc[3][1]);           \
    __builtin_amdgcn_s_setprio(0);                     \
  }

// pslot/pu: slot & kstep of the NEXT phase's fragments (prefetched here)
#define PH8(pslot, pu, ISSUE, WAIT) {                  \
    ISSUE;                                             \
    s16x8 nA0, nA1, nA2, nA3, nB0, nB1;                \
    { const unsigned pc_ = chB[pu];                    \
      DSR(nA0, aB0 + pc_, (pslot) * 16384);            \
      DSR(nA1, aB1 + pc_, (pslot) * 16384);            \
      DSR(nA2, aB2 + pc_, (pslot) * 16384);            \
      DSR(nA3, aB3 + pc_, (pslot) * 16384);            \
      DSR(nB0, bB0 + pc_, (pslot) * 16384);            \
      DSR(nB1, bB1 + pc_, (pslot) * 16384); }          \
    LGKM6;                                             \
    __builtin_amdgcn_sched_barrier(0);                 \
    MM8CLUSTER;                                        \
    cA0 = nA0; cA1 = nA1; cA2 = nA2; cA3 = nA3;        \
    cB0 = nB0; cB1 = nB1;                              \
    WAIT;                                              \
    bar_raw();                                         \
  }

#define PH8_TAIL() { LGKM0; __builtin_amdgcn_sched_barrier(0); MM8CLUSTER; }

__global__ __launch_bounds__(512, 2) void k_gemm8(
    const unsigned short* __restrict__ A, const unsigned short* __restrict__ BT,
    const float* __restrict__ bias, const float* __restrict__ res,
    void* __restrict__ C, int M, int K, int N, int flags, int nb) {
  __shared__ unsigned short As[4 * 256 * 32];  // 64 KB
  __shared__ unsigned short Bs[4 * 256 * 32];  // 64 KB
  (void)M;
  const int t = threadIdx.x;
  const int bid = blockIdx.x;
  const int g = (bid & 7) * (gridDim.x >> 3) + (bid >> 3);  // XCD-aware swizzle (grid%8==0)
  const int n0 = (g % nb) * 256;
  const int m0 = (g / nb) * 256;
  const int lane = t & 63;
  const int w = t >> 6;            // wave 0..7
  const int wm = w >> 2;           // 0..1 -> 128-row half of A-tile
  const int wn = w & 3;            // 0..3 -> 64-col quarter of B-tile
  const int l31 = lane & 31;
  const int ls = lane >> 5;
  const int swz = (lane ^ (lane >> 2)) & 3;  // read-side XOR swizzle (verified 0-conflict)

  const int srow = t >> 2;
  const int gch = ((t & 3) ^ ((srow ^ (srow >> 2)) & 3)) * 8;
  const unsigned short* gA0 = A + (size_t)(m0 + srow) * K + gch;
  const unsigned short* gA1 = A + (size_t)(m0 + srow + 128) * K + gch;
  const unsigned short* gB0 = BT + (size_t)(n0 + srow) * K + gch;
  const unsigned short* gB1 = BT + (size_t)(n0 + srow + 128) * K + gch;
  unsigned short* lA0 = As + t * 8;
  unsigned short* lA1 = As + (t + 512) * 8;
  unsigned short* lB0 = Bs + t * 8;
  unsigned short* lB1 = Bs + (t + 512) * 8;

  const unsigned chB[2] = { (unsigned)(((0 * 2 + ls) ^ swz) * 16),
                            (unsigned)(((1 * 2 + ls) ^ swz) * 16) };
  const unsigned aB0 = laddr(As) + 2u * (unsigned)((wm * 128 + 0 * 32 + l31) * 32);
  const unsigned aB1 = laddr(As) + 2u * (unsigned)((wm * 128 + 1 * 32 + l31) * 32);
  const unsigned aB2 = laddr(As) + 2u * (unsigned)((wm * 128 + 2 * 32 + l31) * 32);
  const unsigned aB3 = laddr(As) + 2u * (unsigned)((wm * 128 + 3 * 32 + l31) * 32);
  const unsigned bB0 = laddr(Bs) + 2u * (unsigned)((wn * 64 + 0 * 32 + l31) * 32);
  const unsigned bB1 = laddr(Bs) + 2u * (unsigned)((wn * 64 + 1 * 32 + l31) * 32);

  f32x16 acc[4][2];
#pragma unroll
  for (int i = 0; i < 4; i++)
#pragma unroll
    for (int j = 0; j < 2; j++)
#pragma unroll
      for (int q = 0; q < 16; q++) acc[i][j][q] = 0.0f;

  const int NT = K >> 6;  // K-tiles of 64; slices (32-K) = 2*NT

  // prologue: stage slices 0,1 + h0(2); slice 0 guaranteed landed (WV4 leaves 2 ISS)
  ISS_H0(0, 0); ISS_H1(0, 0); ISS_H0(1, 1); ISS_H1(1, 1); ISS_H0(2, 2);
  WV4;
  bar_raw();
  // frag[phase 0]: slice 0, slot 0, kstep 0
  s16x8 cA0, cA1, cA2, cA3, cB0, cB1;
  { const unsigned pc_ = chB[0];
    DSR(cA0, aB0 + pc_, 0); DSR(cA1, aB1 + pc_, 0);
    DSR(cA2, aB2 + pc_, 0); DSR(cA3, aB3 + pc_, 0);
    DSR(cB0, bB0 + pc_, 0); DSR(cB1, bB1 + pc_, 0); }

  const int MAIN = (NT - 2) >> 1;
  for (int it = 0; it < MAIN; ++it) {
    const int s0 = 4 * it;
    PH8(0, 1, ISS_H1(s0 + 2, 2), WV4);   // phase j0 (slot0,u0)
    PH8(1, 0, ISS_H0(s0 + 3, 3), WV4);   // j1 (slot0,u1)
    PH8(1, 1, ISS_H1(s0 + 3, 3), WV4);   // j2 (slot1,u0)
    PH8(2, 0, ISS_H0(s0 + 4, 0), WV4);   // j3 (slot1,u1)
    PH8(2, 1, ISS_H1(s0 + 4, 0), WV4);   // j4 (slot2,u0)
    PH8(3, 0, ISS_H0(s0 + 5, 1), WV4);   // j5 (slot2,u1)
    PH8(3, 1, ISS_H1(s0 + 5, 1), WV4);   // j6 (slot3,u0)
    PH8(0, 0, ISS_H0(s0 + 6, 2), WV4);   // j7 (slot3,u1) -> prefetch wraps to slot0
  }
  {
    const int e0 = 2 * NT - 4;  // first of the last 4 slices
    PH8(0, 1, ISS_H1(e0 + 2, 2), WV4);
    PH8(1, 0, ISS_H0(e0 + 3, 3), WV4);
    PH8(1, 1, ISS_H1(e0 + 3, 3), WV4);
    PH8(2, 0, , WV2);
    PH8(2, 1, , WV0);
    PH8(3, 0, , );
    PH8(3, 1, , );
    PH8_TAIL();
  }

  const int rbase = 4 * ls;
  float bsv[2];
#pragma unroll
  for (int nt = 0; nt < 2; nt++) bsv[nt] = bias[n0 + wn * 64 + nt * 32 + l31];
#pragma unroll
  for (int mt = 0; mt < 4; mt++)
#pragma unroll
    for (int nt = 0; nt < 2; nt++)
#pragma unroll
      for (int reg = 0; reg < 16; reg++) {
        const size_t row = (size_t)(m0 + wm * 128 + mt * 32 + rbase + (reg & 3) + 8 * (reg >> 2));
        const int col = n0 + wn * 64 + nt * 32 + l31;
        float v = acc[mt][nt][reg] + bsv[nt];
        if (flags & 1) v = gelu_f(v);
        if (flags & 2) v += res[row * N + col];
        if (flags & 4) ((unsigned short*)C)[row * N + col] = f2bf(v);
        else ((float*)C)[row * N + col] = v;
      }
}

// ---------- bf16 MFMA GEMM: 128x256 tile, 8 waves, 1 phase per 32-K slice ----------
// (out-proj, ff2: 256 blocks -> full fill). Same register-double-buffer discipline:
// prefetch next slice's 8 frags before MFMA, lgkmcnt(8), per-phase vmcnt(3), 1 barrier.
#define ISA_N(sig)  gld16(gA  + (size_t)(sig) * 32, lA  + ((sig) & 3) * 4096)
#define ISB0_N(sig) gld16(gB0 + (size_t)(sig) * 32, lB0 + ((sig) & 3) * 8192)
#define ISB1_N(sig) gld16(gB1 + (size_t)(sig) * 32, lB1 + ((sig) & 3) * 8192)
#define TRIO_N(sig) { ISA_N(sig); ISB0_N(sig); ISB1_N(sig); }

#define MMNCLUSTER {                                   \
    __builtin_amdgcn_s_setprio(1);                     \
    acc[0][0] = MFMA_B(c00, d00, acc[0][0]);           \
    acc[0][1] = MFMA_B(c00, d10, acc[0][1]);           \
    acc[1][0] = MFMA_B(c10, d00, acc[1][0]);           \
    acc[1][1] = MFMA_B(c10, d10, acc[1][1]);           \
    acc[0][0] = MFMA_B(c01, d01, acc[0][0]);           \
    acc[0][1] = MFMA_B(c01, d11, acc[0][1]);           \
    acc[1][0] = MFMA_B(c11, d01, acc[1][0]);           \
    acc[1][1] = MFMA_B(c11, d11, acc[1][1]);           \
    __builtin_amdgcn_s_setprio(0);                     \
  }

#define PHN(pslot, ISSUE, WAIT) {                      \
    ISSUE;                                             \
    s16x8 n00, n10, m00, m10, n01, n11, m01, m11;      \
    DSR(n00, aB0 + cb0, (pslot) * 8192);               \
    DSR(n10, aB1 + cb0, (pslot) * 8192);               \
    DSR(m00, bB0 + cb0, (pslot) * 16384);              \
    DSR(m10, bB1 + cb0, (pslot) * 16384);              \
    DSR(n01, aB0 + cb1, (pslot) * 8192);               \
    DSR(n11, aB1 + cb1, (pslot) * 8192);               \
    DSR(m01, bB0 + cb1, (pslot) * 16384);              \
    DSR(m11, bB1 + cb1, (pslot) * 16384);              \
    LGKM8;                                             \
    __builtin_amdgcn_sched_barrier(0);                 \
    MMNCLUSTER;                                        \
    c00 = n00; c10 = n10; d00 = m00; d10 = m10;        \
    c01 = n01; c11 = n11; d01 = m01; d11 = m11;        \
    WAIT;                                              \
    bar_raw();                                         \
  }

#define PHN_TAIL() { LGKM0; __builtin_amdgcn_sched_barrier(0); MMNCLUSTER; }

__global__ __launch_bounds__(512, 2) void k_gemm8n(
    const unsigned short* __restrict__ A, const unsigned short* __restrict__ BT,
    const float* __restrict__ bias, const float* __restrict__ res,
    void* __restrict__ C, int M, int K, int N, int flags, int nb) {
  __shared__ unsigned short As[4 * 128 * 32];  // 32 KB
  __shared__ unsigned short Bs[4 * 256 * 32];  // 64 KB
  (void)M;
  const int t = threadIdx.x;
  const int bid = blockIdx.x;
  const int g = (bid & 7) * (gridDim.x >> 3) + (bid >> 3);  // XCD swizzle (grid%8==0)
  const int n0 = (g % nb) * 256;
  const int m0 = (g / nb) * 128;
  const int lane = t & 63;
  const int w = t >> 6;            // wave 0..7
  const int wm = w >> 2;           // 0..1 -> 64-row half of A-tile
  const int wn = w & 3;            // 0..3 -> 64-col quarter of B-tile
  const int l31 = lane & 31;
  const int ls = lane >> 5;
  const int swz = (lane ^ (lane >> 2)) & 3;

  const int srow = t >> 2;  // 0..127
  const int gch = ((t & 3) ^ ((srow ^ (srow >> 2)) & 3)) * 8;
  const unsigned short* gA  = A  + (size_t)(m0 + srow) * K + gch;
  const unsigned short* gB0 = BT + (size_t)(n0 + srow) * K + gch;
  const unsigned short* gB1 = BT + (size_t)(n0 + srow + 128) * K + gch;
  unsigned short* lA  = As + t * 8;
  unsigned short* lB0 = Bs + t * 8;
  unsigned short* lB1 = Bs + (t + 512) * 8;

  const unsigned cb0 = (unsigned)(((0 * 2 + ls) ^ swz) * 16);
  const unsigned cb1 = (unsigned)(((1 * 2 + ls) ^ swz) * 16);
  const unsigned aB0 = laddr(As) + 2u * (unsigned)((wm * 64 + l31) * 32);
  const unsigned aB1 = laddr(As) + 2u * (unsigned)((wm * 64 + 32 + l31) * 32);
  const unsigned bB0 = laddr(Bs) + 2u * (unsigned)((wn * 64 + l31) * 32);
  const unsigned bB1 = laddr(Bs) + 2u * (unsigned)((wn * 64 + 32 + l31) * 32);

  f32x16 acc[2][2];
#pragma unroll
  for (int i = 0; i < 2; i++)
#pragma unroll
    for (int j = 0; j < 2; j++)
#pragma unroll
      for (int q = 0; q < 16; q++) acc[i][j][q] = 0.0f;

  const int L = K >> 5;  // 32-K slices (L%4==0, L>=8)

  // prologue: trios 0..2; WV3 -> trios 0,1 landed; frag[0] reads
  TRIO_N(0); TRIO_N(1); TRIO_N(2);
  WV3;
  bar_raw();
  s16x8 c00, c10, d00, d10, c01, c11, d01, d11;
  DSR(c00, aB0 + cb0, 0); DSR(c10, aB1 + cb0, 0);
  DSR(d00, bB0 + cb0, 0); DSR(d10, bB1 + cb0, 0);
  DSR(c01, aB0 + cb1, 0); DSR(c11, aB1 + cb1, 0);
  DSR(d01, bB0 + cb1, 0); DSR(d11, bB1 + cb1, 0);

  const int NIT = (L >> 2) - 1;
  for (int it = 0; it < NIT; ++it) {
    const int s0 = 4 * it;
    PHN(1, TRIO_N(s0 + 3), WV3);
    PHN(2, TRIO_N(s0 + 4), WV3);
    PHN(3, TRIO_N(s0 + 5), WV3);
    PHN(0, TRIO_N(s0 + 6), WV3);
  }
  // last 4 slices L-4..L-1
  PHN(1, TRIO_N(L - 1), WV3);
  PHN(2, , WV0);
  PHN(3, , );
  PHN_TAIL();

  const int rbase = 4 * ls;
  float bsv[2];
#pragma unroll
  for (int nt = 0; nt < 2; nt++) bsv[nt] = bias[n0 + wn * 64 + nt * 32 + l31];
#pragma unroll
  for (int mt = 0; mt < 2; mt++)
#pragma unroll
    for (int nt = 0; nt < 2; nt++)
#pragma unroll
      for (int reg = 0; reg < 16; reg++) {
        const size_t row = (size_t)(m0 + wm * 64 + mt * 32 + rbase + (reg & 3) + 8 * (reg >> 2));
        const int col = n0 + wn * 64 + nt * 32 + l31;
        float v = acc[mt][nt][reg] + bsv[nt];
        if (flags & 1) v = gelu_f(v);
        if (flags & 2) v += res[row * N + col];
        if (flags & 4) ((unsigned short*)C)[row * N + col] = f2bf(v);
        else ((float*)C)[row * N + col] = v;
      }
}

// ---------- Hebbian phase A: per-chunk decayed outer-product sums ----------
__global__ __launch_bounds__(256) void k_heb_chunk(
    const unsigned short* __restrict__ qkv, const float* __restrict__ gam,
    float* __restrict__ U, float* __restrict__ Dc) {
  __shared__ float kw[4096];
  __shared__ float vS[4096];
  __shared__ float cum[64];
  const int bx = blockIdx.x;
  const int c = bx & 31, bh = bx >> 5, b = bh >> 3, h = bh & 7;
  const int t = threadIdx.x;
  const int n0 = c * 64;
  const size_t base = ((size_t)(b * Nn_ + n0)) * 1536 + h * 64;
#pragma unroll
  for (int l = 0; l < 2; l++) {
    const int idx8 = t + 256 * l;
    const int s = idx8 >> 3;
    const int d0 = (idx8 & 7) << 3;
    const size_t gi = base + (size_t)s * 1536 + d0;
    bf8_to_f(qkv + gi + 512, &kw[s * 64 + d0]);
    bf8_to_f(qkv + gi + 1024, &vS[s * 64 + d0]);
  }
  if (t < 64) {
    float val = 0.01f * gam[b * Nn_ + n0 + t];
#pragma unroll
    for (int off = 1; off < 64; off <<= 1) {
      const float o = __shfl_up(val, off, 64);
      if (t >= off) val += o;
    }
    cum[t] = val;
  }
  __syncthreads();
  const float total = cum[63];
#pragma unroll
  for (int l = 0; l < 16; l++) {
    const int idx = t + 256 * l;
    const int s = idx >> 6;
    kw[idx] *= 0.1f * __expf(cum[s] - total);
  }
  __syncthreads();
  const int td = (t & 15) << 2, te = (t >> 4) << 2;
  float acc[4][4];
#pragma unroll
  for (int i = 0; i < 4; i++)
#pragma unroll
    for (int j = 0; j < 4; j++) acc[i][j] = 0.0f;
  for (int s = 0; s < 64; s++) {
    const float4 kk = *(const float4*)&kw[s * 64 + td];
    const float4 vv = *(const float4*)&vS[s * 64 + te];
    const float ka[4] = {kk.x, kk.y, kk.z, kk.w};
    const float va[4] = {vv.x, vv.y, vv.z, vv.w};
#pragma unroll
    for (int i = 0; i < 4; i++)
#pragma unroll
      for (int j = 0; j < 4; j++) acc[i][j] = fmaf(ka[i], va[j], acc[i][j]);
  }
  float* Up = U + (size_t)bx * 4096;
#pragma unroll
  for (int i = 0; i < 4; i++)
#pragma unroll
    for (int j = 0; j < 4; j++) Up[(td + i) * 64 + te + j] = acc[i][j];
  if (t == 0) Dc[bx] = __expf(-total);
}

// ---------- Hebbian phase B: carry W across chunks (one thread per element) ----------
__global__ __launch_bounds__(256) void k_heb_scan(
    const float* __restrict__ U, const float* __restrict__ Dc, float* __restrict__ Win) {
  const int gid = blockIdx.x * 256 + threadIdx.x;   // 0..131071
  const int bh = gid >> 12, el = gid & 4095;
  float w = 0.0f;
#pragma unroll 4
  for (int c = 0; c < 32; c++) {
    const size_t idx = (((size_t)(bh * 32 + c)) << 12) + el;
    Win[idx] = w;
    w = Dc[bh * 32 + c] * w + U[idx];
  }
}

// ---------- Hebbian phase C: intra-chunk causal + inter-chunk q@W_in ----------
__global__ __launch_bounds__(256) void k_heb_out(
    const unsigned short* __restrict__ qkv, const float* __restrict__ gam,
    const float* __restrict__ Win, unsigned short* __restrict__ heb) {
  __shared__ float qS[4096];
  __shared__ float kT[4096];
  __shared__ float vS[4096];
  __shared__ float P[4096];
  const int bx = blockIdx.x;
  const int c = bx & 31, bh = bx >> 5, b = bh >> 3, h = bh & 7;
  const int t = threadIdx.x;
  const int n0 = c * 64;
  const size_t base = ((size_t)(b * Nn_ + n0)) * 1536 + h * 64;
#pragma unroll
  for (int l = 0; l < 2; l++) {
    const int idx8 = t + 256 * l;
    const int s = idx8 >> 3;
    const int d0 = (idx8 & 7) << 3;
    const size_t gi = base + (size_t)s * 1536 + d0;
    bf8_to_f(qkv + gi, &qS[s * 64 + d0]);
    bf8_to_f(qkv + gi + 1024, &vS[s * 64 + d0]);
    float tmp[8];
    bf8_to_f(qkv + gi + 512, tmp);
#pragma unroll
    for (int j = 0; j < 8; j++) kT[(d0 + j) * 64 + s] = tmp[j];
  }
  if (t < 64) {
    float val = 0.01f * gam[b * Nn_ + n0 + t];
#pragma unroll
    for (int off = 1; off < 64; off <<= 1) {
      const float o = __shfl_up(val, off, 64);
      if (t >= off) val += o;
    }
    P[t] = val;
  }
  __syncthreads();
  const int tr = (t >> 4) << 2;
  const int tc = (t & 15) << 2;
  float er[4], es[4];
#pragma unroll
  for (int r = 0; r < 4; r++) er[r] = __expf(-P[tr + r]);
#pragma unroll
  for (int j = 0; j < 4; j++) es[j] = 0.1f * __expf(P[tc + j]);
  __syncthreads();
  float acc[4][4];
#pragma unroll
  for (int i = 0; i < 4; i++)
#pragma unroll
    for (int j = 0; j < 4; j++) acc[i][j] = 0.0f;
  for (int d = 0; d < 64; d++) {
    const float4 kk = *(const float4*)&kT[d * 64 + tc];
    const float ka[4] = {kk.x, kk.y, kk.z, kk.w};
#pragma unroll
    for (int r = 0; r < 4; r++) {
      const float qv = qS[(tr + r) * 64 + d];
#pragma unroll
      for (int j = 0; j < 4; j++) acc[r][j] = fmaf(qv, ka[j], acc[r][j]);
    }
  }
#pragma unroll
  for (int r = 0; r < 4; r++)
#pragma unroll
    for (int j = 0; j < 4; j++) {
      const int tt = tr + r, ssi = tc + j;
      const float wgt = (ssi <= tt) ? er[r] * es[j] : 0.0f;
      P[tt * 64 + ssi] = acc[r][j] * wgt;
    }
  __syncthreads();
  const size_t wb = (size_t)bx * 4096;
#pragma unroll
  for (int l = 0; l < 16; l++) {
    const int idx = t + 256 * l;
    kT[idx] = Win[wb + idx];
  }
  __syncthreads();
  float o1[4][4], o2[4][4];
#pragma unroll
  for (int i = 0; i < 4; i++)
#pragma unroll
    for (int j = 0; j < 4; j++) { o1[i][j] = 0.0f; o2[i][j] = 0.0f; }
  for (int s = 0; s < 64; s++) {
    const float4 vv = *(const float4*)&vS[s * 64 + tc];
    const float4 ww = *(const float4*)&kT[s * 64 + tc];
    const float va[4] = {vv.x, vv.y, vv.z, vv.w};
    const float wa[4] = {ww.x, ww.y, ww.z, ww.w};
#pragma unroll
    for (int r = 0; r < 4; r++) {
      const float pv = P[(tr + r) * 64 + s];
      const float qv = qS[(tr + r) * 64 + s];
#pragma unroll
      for (int j = 0; j < 4; j++) {
        o1[r][j] = fmaf(pv, va[j], o1[r][j]);
        o2[r][j] = fmaf(qv, wa[j], o2[r][j]);
      }
    }
  }
#pragma unroll
  for (int r = 0; r < 4; r++) {
    const int n = n0 + tr + r;
    ushort4 pk;
    pk.x = f2bf(o1[r][0] + er[r] * o2[r][0]);
    pk.y = f2bf(o1[r][1] + er[r] * o2[r][1]);
    pk.z = f2bf(o1[r][2] + er[r] * o2[r][2]);
    pk.w = f2bf(o1[r][3] + er[r] * o2[r][3]);
    *(ushort4*)&heb[((size_t)b * Nn_ + n) * 512 + h * 64 + tc] = pk;
  }
}

extern "C" void kernel_launch(void* const* d_in, const int* in_sizes, int n_in,
                              void* d_out, int out_size, void* d_ws, size_t ws_size,
                              hipStream_t stream) {
  const float* x     = (const float*)d_in[0];
  const float* ln1g  = (const float*)d_in[1];
  const float* ln1b  = (const float*)d_in[2];
  const float* ln2g  = (const float*)d_in[3];
  const float* ln2b  = (const float*)d_in[4];
  const float* ln3g  = (const float*)d_in[5];
  const float* ln3b  = (const float*)d_in[6];
  const float* w_pot = (const float*)d_in[7];
  const float* b_pot = (const float*)d_in[8];
  const float* w_bk  = (const float*)d_in[9];
  const float* b_bk  = (const float*)d_in[10];
  const float* w_qkv = (const float*)d_in[11];
  const float* b_qkv = (const float*)d_in[12];
  const float* w_out = (const float*)d_in[13];
  const float* b_out = (const float*)d_in[14];
  const float* w_ff1 = (const float*)d_in[15];
  const float* b_ff1 = (const float*)d_in[16];
  const float* w_ff2 = (const float*)d_in[17];
  const float* b_ff2 = (const float*)d_in[18];
  float* out = (float*)d_out;
  float* ws = (float*)d_ws;

  // ---- workspace layout (float units), total 34,668,544 floats = 138.7 MB ----
  float* V   = ws;
  float* gam = V + 8192;
  float* aRe = gam + 8192;
  float* aIm = aRe + 8192;
  float* bRe = aIm + 8192;
  float* bIm = bRe + 8192;
  float* Dc  = bIm + 8192;
  float* HID = ws + 65536;             // 16.78M f32 (67.1MB): x1 + qkv early; ff hidden late
  float* x1   = HID;                   // 8.39M f32
  unsigned short* qkvb = (unsigned short*)(HID + 8388608);  // 12.58M shorts
  unsigned short* hid  = (unsigned short*)HID;              // 8192x4096 bf16 (ff phase)
  float* RC   = HID + 16777216;        // 8.39M f32: U+Win, later x2
  float* U    = RC;
  float* Win  = RC + 4194304;
  float* x2   = RC;
  float* RD   = RC + 8388608;          // 4.19M f32: xn2/heb/xn3 (bf16)
  unsigned short* xnb = (unsigned short*)RD;
  unsigned short* heb = (unsigned short*)RD;
  unsigned short* wE  = (unsigned short*)(RD + 4194304);
  unsigned short* wqkvT = wE;                    // 1536x1024
  unsigned short* woutT = wqkvT + 1572864;       // 1024x512
  unsigned short* wff1T = woutT + 524288;        // 4096x1024
  unsigned short* wff2T = wff1T + 4194304;       // 1024x4096

  // weight transposes (fp32 KxN -> bf16 NxK)
  k_wt<<<dim3(1536 / 32, 1024 / 32), 256, 0, stream>>>(w_qkv, wqkvT, 1024, 1536);
  k_wt<<<dim3(1024 / 32, 512 / 32), 256, 0, stream>>>(w_out, woutT, 512, 1024);
  k_wt<<<dim3(4096 / 32, 1024 / 32), 256, 0, stream>>>(w_ff1, wff1T, 1024, 4096);
  k_wt<<<dim3(1024 / 32, 4096 / 32), 256, 0, stream>>>(w_ff2, wff2T, 4096, 1024);

  k_ln_pot<<<Tt, 256, 0, stream>>>(x, ln1g, ln1b, w_pot, b_pot, V, gam);
  k_cf_par<<<8, 64, 0, stream>>>(V, gam, aRe, aIm, bRe, bIm);
  k_bk_add<<<Tt, 256, 0, stream>>>(x, aRe, aIm, bRe, bIm, V, gam, w_bk, b_bk, x1);
  k_ln_bf<<<Tt, 256, 0, stream>>>(x1, ln2g, ln2b, xnb);
  // qkv: (8192x1024)@(1024x1536) -> bf16   [256^2 tile, nb=6, 192 blocks]
  k_gemm8<<<192, 512, 0, stream>>>(xnb, wqkvT, b_qkv, nullptr, qkvb,
                                   8192, 1024, 1536, 4, 6);
  k_heb_chunk<<<1024, 256, 0, stream>>>(qkvb, gam, U, Dc);
  k_heb_scan<<<512, 256, 0, stream>>>(U, Dc, Win);
  k_heb_out<<<1024, 256, 0, stream>>>(qkvb, gam, Win, heb);
  // out-proj: (8192x512)@(512x1024) + x1 -> f32 x2   [128x256 tile, nb=4, 256 blocks]
  k_gemm8n<<<256, 512, 0, stream>>>(heb, woutT, b_out, x1, x2,
                                    8192, 512, 1024, 2, 4);
  k_ln_bf<<<Tt, 256, 0, stream>>>(x2, ln3g, ln3b, xnb);
  // ff1: (8192x1024)@(1024x4096) gelu -> bf16 hid   [256^2 tile, nb=16, 512 blocks]
  k_gemm8<<<512, 512, 0, stream>>>(xnb, wff1T, b_ff1, nullptr, hid,
                                   8192, 1024, 4096, 1 | 4, 16);
  // ff2: (8192x4096)@(4096x1024) + x2 -> f32 out   [128x256 tile, nb=4, 256 blocks]
  k_gemm8n<<<256, 512, 0, stream>>>(hid, wff2T, b_ff2, x2, out,
                                    8192, 4096, 1024, 2, 4);
}

// Round 5
// 507.206 us; speedup vs baseline: 1.0443x; 1.0210x over previous
//
#include <hip/hip_runtime.h>

#define Bn 4
#define Nn_ 2048
#define Dd 1024
#define Hh 8
#define HDd 64
#define Tt 8192   // Bn*Nn_

typedef short s16x8 __attribute__((ext_vector_type(8)));
typedef float f32x4 __attribute__((ext_vector_type(4)));
typedef float f32x16 __attribute__((ext_vector_type(16)));

__device__ __forceinline__ unsigned short f2bf(float f) {
  unsigned u = __float_as_uint(f);
  return (unsigned short)((u + 0x7fffu + ((u >> 16) & 1u)) >> 16);
}

__device__ __forceinline__ void bf8_to_f(const unsigned short* p, float* o) {
  const uint4 u = *(const uint4*)p;
  o[0] = __uint_as_float(u.x << 16);
  o[1] = __uint_as_float(u.x & 0xffff0000u);
  o[2] = __uint_as_float(u.y << 16);
  o[3] = __uint_as_float(u.y & 0xffff0000u);
  o[4] = __uint_as_float(u.z << 16);
  o[5] = __uint_as_float(u.z & 0xffff0000u);
  o[6] = __uint_as_float(u.w << 16);
  o[7] = __uint_as_float(u.w & 0xffff0000u);
}

__device__ __forceinline__ void gld16(const void* g, void* l) {
  __builtin_amdgcn_global_load_lds(
      (const __attribute__((address_space(1))) unsigned int*)(uintptr_t)g,
      (__attribute__((address_space(3))) unsigned int*)(uintptr_t)l, 16, 0, 0);
}

__device__ __forceinline__ void bar_raw() { asm volatile("s_barrier" ::: "memory"); }

__device__ __forceinline__ unsigned laddr(const void* p) {
  return (unsigned)(uintptr_t)p;
}

// inline-asm ds_read_b128 (opaque to alias analysis)
#define DSR(dst, a, imm) \
  asm volatile("ds_read_b128 %0, %1 offset:%2" : "=v"(dst) : "v"(a), "n"(imm))

__device__ __forceinline__ void block_reduce2(float& a, float& b, float* sc) {
#pragma unroll
  for (int off = 32; off > 0; off >>= 1) {
    a += __shfl_down(a, off, 64);
    b += __shfl_down(b, off, 64);
  }
  __syncthreads();
  if ((threadIdx.x & 63) == 0) { int wid = threadIdx.x >> 6; sc[wid] = a; sc[4 + wid] = b; }
  __syncthreads();
  a = sc[0] + sc[1] + sc[2] + sc[3];
  b = sc[4] + sc[5] + sc[6] + sc[7];
}

__device__ __forceinline__ float gelu_f(float u) {
  const float c = 0.7978845608028654f * (u + 0.044715f * u * u * u);
  const float e = __expf(2.0f * c);
  const float th = 1.0f - 2.0f / (1.0f + e);
  return 0.5f * u * (1.0f + th);
}

// ---------- weight convert+transpose: W (KxN f32) -> WT (NxK bf16) ----------
__global__ __launch_bounds__(256) void k_wt(const float* __restrict__ W,
                                            unsigned short* __restrict__ WT, int K, int N) {
  __shared__ float tile[32][33];
  const int n0 = blockIdx.x * 32, k0 = blockIdx.y * 32;
  const int tx = threadIdx.x & 31, ty = threadIdx.x >> 5;  // ty 0..7
#pragma unroll
  for (int i = 0; i < 4; i++) {
    const int kk = ty + i * 8;
    tile[kk][tx] = W[(size_t)(k0 + kk) * N + n0 + tx];
  }
  __syncthreads();
#pragma unroll
  for (int i = 0; i < 4; i++) {
    const int nn = ty + i * 8;
    WT[(size_t)(n0 + nn) * K + k0 + tx] = f2bf(tile[tx][nn]);
  }
}

// ---------- LN1 + potential projection (V, gamma) ----------
__global__ __launch_bounds__(256) void k_ln_pot(
    const float* __restrict__ x, const float* __restrict__ g, const float* __restrict__ bt,
    const float* __restrict__ w_pot, const float* __restrict__ b_pot,
    float* __restrict__ V, float* __restrict__ gam) {
  __shared__ float sc[8];
  const int m = blockIdx.x, t = threadIdx.x;
  const float4 xv = ((const float4*)(x + (size_t)m * Dd))[t];
  float s = xv.x + xv.y + xv.z + xv.w;
  float ss = fmaf(xv.x, xv.x, fmaf(xv.y, xv.y, fmaf(xv.z, xv.z, xv.w * xv.w)));
  block_reduce2(s, ss, sc);
  const float mean = s * (1.0f / Dd);
  const float var = ss * (1.0f / Dd) - mean * mean;
  const float rs = rsqrtf(var + 1e-5f);
  const float4 gv = ((const float4*)g)[t];
  const float4 bv = ((const float4*)bt)[t];
  const float xn0 = (xv.x - mean) * rs * gv.x + bv.x;
  const float xn1 = (xv.y - mean) * rs * gv.y + bv.y;
  const float xn2 = (xv.z - mean) * rs * gv.z + bv.z;
  const float xn3 = (xv.w - mean) * rs * gv.w + bv.w;
  const float4 wp0 = ((const float4*)w_pot)[t * 2];
  const float4 wp1 = ((const float4*)w_pot)[t * 2 + 1];
  float s0 = xn0 * wp0.x + xn1 * wp0.z + xn2 * wp1.x + xn3 * wp1.z;
  float s1 = xn0 * wp0.y + xn1 * wp0.w + xn2 * wp1.y + xn3 * wp1.w;
  block_reduce2(s0, s1, sc);
  if (t == 0) {
    V[m] = s0 + b_pot[0];
    const float p1 = s1 + b_pot[1];
    const float sp = fmaxf(p1, 0.0f) + log1pf(expf(-fabsf(p1)));
    gam[m] = sp + 0.1f;
  }
}

// ---------- parallel continued fraction scan (Mobius matrix scan + replay) ----------
__global__ void k_cf_par(const float* __restrict__ V, const float* __restrict__ gam,
                         float* __restrict__ aRe, float* __restrict__ aIm,
                         float* __restrict__ bRe, float* __restrict__ bIm) {
  const int b = blockIdx.x >> 1, dir = blockIdx.x & 1;
  const int l = threadIdx.x;  // 0..63
  const float* Vb = V + b * Nn_;
  const float* gb = gam + b * Nn_;
  float m[8] = {1.f, 0.f, 0.f, 0.f, 0.f, 0.f, 1.f, 0.f};
#pragma unroll 4
  for (int s = 0; s < 32; s++) {
    const int j = l * 32 + s;
    const int i = dir ? (Nn_ - 1 - j) : j;
    const float dre = Vb[i] + 2.0f, dim = -gb[i];
    const float n00r = dre * m[0] - dim * m[1] - m[4];
    const float n00i = dre * m[1] + dim * m[0] - m[5];
    const float n01r = dre * m[2] - dim * m[3] - m[6];
    const float n01i = dre * m[3] + dim * m[2] - m[7];
    m[4] = m[0]; m[5] = m[1]; m[6] = m[2]; m[7] = m[3];
    m[0] = n00r; m[1] = n00i; m[2] = n01r; m[3] = n01i;
    const float rr = 1.0f / (fabsf(m[0]) + fabsf(m[1]) + fabsf(m[4]) + fabsf(m[5]));
#pragma unroll
    for (int q = 0; q < 8; q++) m[q] *= rr;
  }
#pragma unroll
  for (int off = 1; off < 64; off <<= 1) {
    float p[8];
#pragma unroll
    for (int q = 0; q < 8; q++) p[q] = __shfl_up(m[q], off, 64);
    if (l < off) { p[0] = 1.f; p[1] = 0.f; p[2] = 0.f; p[3] = 0.f;
                   p[4] = 0.f; p[5] = 0.f; p[6] = 1.f; p[7] = 0.f; }
    float c[8];
    c[0] = m[0] * p[0] - m[1] * p[1] + m[2] * p[4] - m[3] * p[5];
    c[1] = m[0] * p[1] + m[1] * p[0] + m[2] * p[5] + m[3] * p[4];
    c[2] = m[0] * p[2] - m[1] * p[3] + m[2] * p[6] - m[3] * p[7];
    c[3] = m[0] * p[3] + m[1] * p[2] + m[2] * p[7] + m[3] * p[6];
    c[4] = m[4] * p[0] - m[5] * p[1] + m[6] * p[4] - m[7] * p[5];
    c[5] = m[4] * p[1] + m[5] * p[0] + m[6] * p[5] + m[7] * p[4];
    c[6] = m[4] * p[2] - m[5] * p[3] + m[6] * p[6] - m[7] * p[7];
    c[7] = m[4] * p[3] + m[5] * p[2] + m[6] * p[7] + m[7] * p[6];
    const float rr = 1.0f / (fabsf(c[0]) + fabsf(c[1]) + fabsf(c[4]) + fabsf(c[5]));
#pragma unroll
    for (int q = 0; q < 8; q++) m[q] = c[q] * rr;
  }
  float e[8];
#pragma unroll
  for (int q = 0; q < 8; q++) e[q] = __shfl_up(m[q], 1, 64);
  if (l == 0) { e[0] = 1.f; e[1] = 0.f; e[4] = 0.f; e[5] = 0.f; }
  const float inr = 1.0f / (e[0] * e[0] + e[1] * e[1]);
  float pr = (e[4] * e[0] + e[5] * e[1]) * inr;
  float pi = (e[5] * e[0] - e[4] * e[1]) * inr;
  float* oR = dir ? bRe : aRe;
  float* oI = dir ? bIm : aIm;
#pragma unroll 4
  for (int s = 0; s < 32; s++) {
    const int j = l * 32 + s;
    const int i = dir ? (Nn_ - 1 - j) : j;
    const float dre = Vb[i] + 2.0f, dim = -gb[i];
    const float ar = dre - pr, ai = dim - pi;
    oR[b * Nn_ + i] = ar; oI[b * Nn_ + i] = ai;
    const float r = 1.0f / (ar * ar + ai * ai);
    pr = ar * r; pi = -ai * r;
  }
}

// ---------- x1 = x + [G.re,G.im] @ w_bk + b_bk ----------
__global__ __launch_bounds__(256) void k_bk_add(
    const float* __restrict__ x, const float* __restrict__ aRe, const float* __restrict__ aIm,
    const float* __restrict__ bRe, const float* __restrict__ bIm,
    const float* __restrict__ V, const float* __restrict__ gam,
    const float* __restrict__ w_bk, const float* __restrict__ b_bk, float* __restrict__ x1) {
  const int m = blockIdx.x, t = threadIdx.x;
  const float dre = V[m] + 2.0f, dim = -gam[m];
  const float nr = aRe[m] + bRe[m] - dre;
  const float ni = aIm[m] + bIm[m] - dim;
  const float r = 1.0f / (nr * nr + ni * ni);
  const float Gre = nr * r, Gim = -ni * r;
  const float4 xv = ((const float4*)(x + (size_t)m * Dd))[t];
  const float4 w0 = ((const float4*)w_bk)[t];
  const float4 w1 = ((const float4*)(w_bk + Dd))[t];
  const float4 bb = ((const float4*)b_bk)[t];
  float4 o;
  o.x = xv.x + Gre * w0.x + Gim * w1.x + bb.x;
  o.y = xv.y + Gre * w0.y + Gim * w1.y + bb.y;
  o.z = xv.z + Gre * w0.z + Gim * w1.z + bb.z;
  o.w = xv.w + Gre * w0.w + Gim * w1.w + bb.w;
  ((float4*)(x1 + (size_t)m * Dd))[t] = o;
}

// ---------- layernorm -> bf16 output ----------
__global__ __launch_bounds__(256) void k_ln_bf(
    const float* __restrict__ x, const float* __restrict__ g, const float* __restrict__ bt,
    unsigned short* __restrict__ y) {
  __shared__ float sc[8];
  const int m = blockIdx.x, t = threadIdx.x;
  const float4 xv = ((const float4*)(x + (size_t)m * Dd))[t];
  float s = xv.x + xv.y + xv.z + xv.w;
  float ss = fmaf(xv.x, xv.x, fmaf(xv.y, xv.y, fmaf(xv.z, xv.z, xv.w * xv.w)));
  block_reduce2(s, ss, sc);
  const float mean = s * (1.0f / Dd);
  const float var = ss * (1.0f / Dd) - mean * mean;
  const float rs = rsqrtf(var + 1e-5f);
  const float4 gv = ((const float4*)g)[t];
  const float4 bv = ((const float4*)bt)[t];
  ushort4 pk;
  pk.x = f2bf((xv.x - mean) * rs * gv.x + bv.x);
  pk.y = f2bf((xv.y - mean) * rs * gv.y + bv.y);
  pk.z = f2bf((xv.z - mean) * rs * gv.z + bv.z);
  pk.w = f2bf((xv.w - mean) * rs * gv.w + bv.w);
  ((ushort4*)(y + (size_t)m * Dd))[t] = pk;
}

// ---------- bf16 MFMA GEMM: 256x256 tile, 8 waves, merged 32-K phases ----------
// Phase = one 32-K slice: 12 ds_read_b128, lgkmcnt(6)->8 MFMA(k0), lgkmcnt(0)->8 MFMA(k1),
// vmcnt(4), ONE barrier. 32 phases at K=1024 (was 64) -> per-phase sync cost amortized 2x.
// Ring: slice s in slot s&3; H0 staged at phase s-3, H1 at s-2; WV4 at end of s-1
// proves both retired before phase s reads. Write-slots (p+2)&3,(p+3)&3 disjoint from
// read slot p&3 and protected by the end-of-phase barrier.
#define ISS_H0(sig, slot) { gld16(gA0 + (size_t)(sig) * 32, lA0 + (slot) * 8192); \
                            gld16(gB0 + (size_t)(sig) * 32, lB0 + (slot) * 8192); }
#define ISS_H1(sig, slot) { gld16(gA1 + (size_t)(sig) * 32, lA1 + (slot) * 8192); \
                            gld16(gB1 + (size_t)(sig) * 32, lB1 + (slot) * 8192); }
#define WV4 asm volatile("s_waitcnt vmcnt(4)" ::: "memory")
#define WV2 asm volatile("s_waitcnt vmcnt(2)" ::: "memory")
#define WV0 asm volatile("s_waitcnt vmcnt(0)" ::: "memory")
#define MFMA_B(a, b, c) __builtin_amdgcn_mfma_f32_32x32x16_bf16(a, b, c, 0, 0, 0)

#define PH8M_CORE(slot)                                             \
    s16x8 a00, a10, a20, a30, b00, b10;                             \
    s16x8 a01, a11, a21, a31, b01, b11;                             \
    DSR(a00, aB0 + ch0, (slot) * 16384);                            \
    DSR(a10, aB1 + ch0, (slot) * 16384);                            \
    DSR(a20, aB2 + ch0, (slot) * 16384);                            \
    DSR(a30, aB3 + ch0, (slot) * 16384);                            \
    DSR(b00, bB0 + ch0, (slot) * 16384);                            \
    DSR(b10, bB1 + ch0, (slot) * 16384);                            \
    DSR(a01, aB0 + ch1, (slot) * 16384);                            \
    DSR(a11, aB1 + ch1, (slot) * 16384);                            \
    DSR(a21, aB2 + ch1, (slot) * 16384);                            \
    DSR(a31, aB3 + ch1, (slot) * 16384);                            \
    DSR(b01, bB0 + ch1, (slot) * 16384);                            \
    DSR(b11, bB1 + ch1, (slot) * 16384);                            \
    asm volatile("s_waitcnt lgkmcnt(6)" ::: "memory");              \
    __builtin_amdgcn_sched_barrier(0);                              \
    __builtin_amdgcn_s_setprio(1);                                  \
    acc[0][0] = MFMA_B(a00, b00, acc[0][0]);                        \
    acc[0][1] = MFMA_B(a00, b10, acc[0][1]);                        \
    acc[1][0] = MFMA_B(a10, b00, acc[1][0]);                        \
    acc[1][1] = MFMA_B(a10, b10, acc[1][1]);                        \
    acc[2][0] = MFMA_B(a20, b00, acc[2][0]);                        \
    acc[2][1] = MFMA_B(a20, b10, acc[2][1]);                        \
    acc[3][0] = MFMA_B(a30, b00, acc[3][0]);                        \
    acc[3][1] = MFMA_B(a30, b10, acc[3][1]);                        \
    asm volatile("s_waitcnt lgkmcnt(0)" ::: "memory");              \
    __builtin_amdgcn_sched_barrier(0);                              \
    acc[0][0] = MFMA_B(a01, b01, acc[0][0]);                        \
    acc[0][1] = MFMA_B(a01, b11, acc[0][1]);                        \
    acc[1][0] = MFMA_B(a11, b01, acc[1][0]);                        \
    acc[1][1] = MFMA_B(a11, b11, acc[1][1]);                        \
    acc[2][0] = MFMA_B(a21, b01, acc[2][0]);                        \
    acc[2][1] = MFMA_B(a21, b11, acc[2][1]);                        \
    acc[3][0] = MFMA_B(a31, b01, acc[3][0]);                        \
    acc[3][1] = MFMA_B(a31, b11, acc[3][1]);                        \
    __builtin_amdgcn_s_setprio(0);

#define PH8M(slot, ISSUE, WAIT) { ISSUE; PH8M_CORE(slot); WAIT; bar_raw(); }
#define PH8M_LAST(slot) { PH8M_CORE(slot); }

__global__ __launch_bounds__(512, 2) void k_gemm8(
    const unsigned short* __restrict__ A, const unsigned short* __restrict__ BT,
    const float* __restrict__ bias, const float* __restrict__ res,
    void* __restrict__ C, int M, int K, int N, int flags, int nb) {
  __shared__ unsigned short As[4 * 256 * 32];  // 64 KB
  __shared__ unsigned short Bs[4 * 256 * 32];  // 64 KB
  (void)M;
  const int t = threadIdx.x;
  const int bid = blockIdx.x;
  const int g = (bid & 7) * (gridDim.x >> 3) + (bid >> 3);  // XCD-aware swizzle (grid%8==0)
  const int n0 = (g % nb) * 256;
  const int m0 = (g / nb) * 256;
  const int lane = t & 63;
  const int w = t >> 6;            // wave 0..7
  const int wm = w >> 2;           // 0..1 -> 128-row half of A-tile
  const int wn = w & 3;            // 0..3 -> 64-col quarter of B-tile
  const int l31 = lane & 31;
  const int ls = lane >> 5;
  const int swz = (lane ^ (lane >> 2)) & 3;  // read-side XOR swizzle (verified 0-conflict)

  const int srow = t >> 2;
  const int gch = ((t & 3) ^ ((srow ^ (srow >> 2)) & 3)) * 8;
  const unsigned short* gA0 = A + (size_t)(m0 + srow) * K + gch;
  const unsigned short* gA1 = A + (size_t)(m0 + srow + 128) * K + gch;
  const unsigned short* gB0 = BT + (size_t)(n0 + srow) * K + gch;
  const unsigned short* gB1 = BT + (size_t)(n0 + srow + 128) * K + gch;
  unsigned short* lA0 = As + t * 8;
  unsigned short* lA1 = As + (t + 512) * 8;
  unsigned short* lB0 = Bs + t * 8;
  unsigned short* lB1 = Bs + (t + 512) * 8;

  const unsigned ch0 = (unsigned)(((0 * 2 + ls) ^ swz) * 16);
  const unsigned ch1 = (unsigned)(((1 * 2 + ls) ^ swz) * 16);
  const unsigned aB0 = laddr(As) + 2u * (unsigned)((wm * 128 + 0 * 32 + l31) * 32);
  const unsigned aB1 = laddr(As) + 2u * (unsigned)((wm * 128 + 1 * 32 + l31) * 32);
  const unsigned aB2 = laddr(As) + 2u * (unsigned)((wm * 128 + 2 * 32 + l31) * 32);
  const unsigned aB3 = laddr(As) + 2u * (unsigned)((wm * 128 + 3 * 32 + l31) * 32);
  const unsigned bB0 = laddr(Bs) + 2u * (unsigned)((wn * 64 + 0 * 32 + l31) * 32);
  const unsigned bB1 = laddr(Bs) + 2u * (unsigned)((wn * 64 + 1 * 32 + l31) * 32);

  f32x16 acc[4][2];
#pragma unroll
  for (int i = 0; i < 4; i++)
#pragma unroll
    for (int j = 0; j < 2; j++)
#pragma unroll
      for (int q = 0; q < 16; q++) acc[i][j][q] = 0.0f;

  const int NS = K >> 5;  // 32-K slices (NS%4==0, NS>=12)

  // prologue: slices 0,1 fully + H0(2); WV2 -> slices 0,1 landed
  ISS_H0(0, 0); ISS_H1(0, 0); ISS_H0(1, 1); ISS_H1(1, 1); ISS_H0(2, 2);
  WV2;
  bar_raw();

  const int MAIN = (NS >> 2) - 2;
  for (int it = 0; it < MAIN; ++it) {
    const int s0 = 4 * it;
    PH8M(0, { ISS_H1(s0 + 2, 2); ISS_H0(s0 + 3, 3); }, WV4);
    PH8M(1, { ISS_H1(s0 + 3, 3); ISS_H0(s0 + 4, 0); }, WV4);
    PH8M(2, { ISS_H1(s0 + 4, 0); ISS_H0(s0 + 5, 1); }, WV4);
    PH8M(3, { ISS_H1(s0 + 5, 1); ISS_H0(s0 + 6, 2); }, WV4);
  }
  {
    const int e = NS - 8;  // slot (e&3)==0 since NS%4==0
    PH8M(0, { ISS_H1(e + 2, 2); ISS_H0(e + 3, 3); }, WV4);
    PH8M(1, { ISS_H1(e + 3, 3); ISS_H0(e + 4, 0); }, WV4);
    PH8M(2, { ISS_H1(e + 4, 0); ISS_H0(e + 5, 1); }, WV4);
    PH8M(3, { ISS_H1(e + 5, 1); ISS_H0(e + 6, 2); }, WV4);
    PH8M(0, { ISS_H1(e + 6, 2); ISS_H0(e + 7, 3); }, WV4);
    PH8M(1, { ISS_H1(e + 7, 3); }, WV2);
    PH8M(2, , WV0);
    PH8M_LAST(3);
  }

  const int rbase = 4 * ls;
  float bsv[2];
#pragma unroll
  for (int nt = 0; nt < 2; nt++) bsv[nt] = bias[n0 + wn * 64 + nt * 32 + l31];
#pragma unroll
  for (int mt = 0; mt < 4; mt++)
#pragma unroll
    for (int nt = 0; nt < 2; nt++)
#pragma unroll
      for (int reg = 0; reg < 16; reg++) {
        const size_t row = (size_t)(m0 + wm * 128 + mt * 32 + rbase + (reg & 3) + 8 * (reg >> 2));
        const int col = n0 + wn * 64 + nt * 32 + l31;
        float v = acc[mt][nt][reg] + bsv[nt];
        if (flags & 1) v = gelu_f(v);
        if (flags & 2) v += res[row * N + col];
        if (flags & 4) ((unsigned short*)C)[row * N + col] = f2bf(v);
        else ((float*)C)[row * N + col] = v;
      }
}

// ---------- bf16 MFMA GEMM: 128x256 tile, 8 waves, merged 64-K phases ----------
// (out-proj, ff2: 256 blocks -> full fill). Phase = 2 slices (16 MFMA, 16 ds_reads,
// lgkm 8/0 split). Pair double-buffer: read slots {0,1} while staging {2,3} and vice
// versa; vmcnt(0) at phase end (in-flight ~= full phase >> HBM latency -> cheap).
#define ISA_N(sig)  gld16(gA  + (size_t)(sig) * 32, lA  + ((sig) & 3) * 4096)
#define ISB0_N(sig) gld16(gB0 + (size_t)(sig) * 32, lB0 + ((sig) & 3) * 8192)
#define ISB1_N(sig) gld16(gB1 + (size_t)(sig) * 32, lB1 + ((sig) & 3) * 8192)
#define TRIO_N(sig) { ISA_N(sig); ISB0_N(sig); ISB1_N(sig); }

#define PHNM_CORE(slo, shi)                                         \
    s16x8 p00, p10, q00, q10, p01, p11, q01, q11;                   \
    s16x8 r00, r10, s00, s10, r01, r11, s01, s11;                   \
    DSR(p00, aB0 + cb0, (slo) * 8192);                              \
    DSR(p10, aB1 + cb0, (slo) * 8192);                              \
    DSR(q00, bB0 + cb0, (slo) * 16384);                             \
    DSR(q10, bB1 + cb0, (slo) * 16384);                             \
    DSR(p01, aB0 + cb1, (slo) * 8192);                              \
    DSR(p11, aB1 + cb1, (slo) * 8192);                              \
    DSR(q01, bB0 + cb1, (slo) * 16384);                             \
    DSR(q11, bB1 + cb1, (slo) * 16384);                             \
    DSR(r00, aB0 + cb0, (shi) * 8192);                              \
    DSR(r10, aB1 + cb0, (shi) * 8192);                              \
    DSR(s00, bB0 + cb0, (shi) * 16384);                             \
    DSR(s10, bB1 + cb0, (shi) * 16384);                             \
    DSR(r01, aB0 + cb1, (shi) * 8192);                              \
    DSR(r11, aB1 + cb1, (shi) * 8192);                              \
    DSR(s01, bB0 + cb1, (shi) * 16384);                             \
    DSR(s11, bB1 + cb1, (shi) * 16384);                             \
    asm volatile("s_waitcnt lgkmcnt(8)" ::: "memory");              \
    __builtin_amdgcn_sched_barrier(0);                              \
    __builtin_amdgcn_s_setprio(1);                                  \
    acc[0][0] = MFMA_B(p00, q00, acc[0][0]);                        \
    acc[0][1] = MFMA_B(p00, q10, acc[0][1]);                        \
    acc[1][0] = MFMA_B(p10, q00, acc[1][0]);                        \
    acc[1][1] = MFMA_B(p10, q10, acc[1][1]);                        \
    acc[0][0] = MFMA_B(p01, q01, acc[0][0]);                        \
    acc[0][1] = MFMA_B(p01, q11, acc[0][1]);                        \
    acc[1][0] = MFMA_B(p11, q01, acc[1][0]);                        \
    acc[1][1] = MFMA_B(p11, q11, acc[1][1]);                        \
    asm volatile("s_waitcnt lgkmcnt(0)" ::: "memory");              \
    __builtin_amdgcn_sched_barrier(0);                              \
    acc[0][0] = MFMA_B(r00, s00, acc[0][0]);                        \
    acc[0][1] = MFMA_B(r00, s10, acc[0][1]);                        \
    acc[1][0] = MFMA_B(r10, s00, acc[1][0]);                        \
    acc[1][1] = MFMA_B(r10, s10, acc[1][1]);                        \
    acc[0][0] = MFMA_B(r01, s01, acc[0][0]);                        \
    acc[0][1] = MFMA_B(r01, s11, acc[0][1]);                        \
    acc[1][0] = MFMA_B(r11, s01, acc[1][0]);                        \
    acc[1][1] = MFMA_B(r11, s11, acc[1][1]);                        \
    __builtin_amdgcn_s_setprio(0);

#define PHNM(slo, shi, ISSUE, WAIT) { ISSUE; PHNM_CORE(slo, shi); WAIT; bar_raw(); }
#define PHNM_LAST(slo, shi) { PHNM_CORE(slo, shi); }

__global__ __launch_bounds__(512, 2) void k_gemm8n(
    const unsigned short* __restrict__ A, const unsigned short* __restrict__ BT,
    const float* __restrict__ bias, const float* __restrict__ res,
    void* __restrict__ C, int M, int K, int N, int flags, int nb) {
  __shared__ unsigned short As[4 * 128 * 32];  // 32 KB
  __shared__ unsigned short Bs[4 * 256 * 32];  // 64 KB
  (void)M;
  const int t = threadIdx.x;
  const int bid = blockIdx.x;
  const int g = (bid & 7) * (gridDim.x >> 3) + (bid >> 3);  // XCD swizzle (grid%8==0)
  const int n0 = (g % nb) * 256;
  const int m0 = (g / nb) * 128;
  const int lane = t & 63;
  const int w = t >> 6;            // wave 0..7
  const int wm = w >> 2;           // 0..1 -> 64-row half of A-tile
  const int wn = w & 3;            // 0..3 -> 64-col quarter of B-tile
  const int l31 = lane & 31;
  const int ls = lane >> 5;
  const int swz = (lane ^ (lane >> 2)) & 3;

  const int srow = t >> 2;  // 0..127
  const int gch = ((t & 3) ^ ((srow ^ (srow >> 2)) & 3)) * 8;
  const unsigned short* gA  = A  + (size_t)(m0 + srow) * K + gch;
  const unsigned short* gB0 = BT + (size_t)(n0 + srow) * K + gch;
  const unsigned short* gB1 = BT + (size_t)(n0 + srow + 128) * K + gch;
  unsigned short* lA  = As + t * 8;
  unsigned short* lB0 = Bs + t * 8;
  unsigned short* lB1 = Bs + (t + 512) * 8;

  const unsigned cb0 = (unsigned)(((0 * 2 + ls) ^ swz) * 16);
  const unsigned cb1 = (unsigned)(((1 * 2 + ls) ^ swz) * 16);
  const unsigned aB0 = laddr(As) + 2u * (unsigned)((wm * 64 + l31) * 32);
  const unsigned aB1 = laddr(As) + 2u * (unsigned)((wm * 64 + 32 + l31) * 32);
  const unsigned bB0 = laddr(Bs) + 2u * (unsigned)((wn * 64 + l31) * 32);
  const unsigned bB1 = laddr(Bs) + 2u * (unsigned)((wn * 64 + 32 + l31) * 32);

  f32x16 acc[2][2];
#pragma unroll
  for (int i = 0; i < 2; i++)
#pragma unroll
    for (int j = 0; j < 2; j++)
#pragma unroll
      for (int q = 0; q < 16; q++) acc[i][j][q] = 0.0f;

  const int L = K >> 5;  // 32-K slices (L%4==0, L>=8); phases = L/2

  // prologue: slices 0,1 -> slots 0,1; drain
  TRIO_N(0); TRIO_N(1);
  WV0;
  bar_raw();

  const int MM = (L >> 2) - 1;  // pair-iterations covering phases 0..L/2-3
  for (int it = 0; it < MM; ++it) {
    const int s0 = 4 * it;
    PHNM(0, 1, { TRIO_N(s0 + 2); TRIO_N(s0 + 3); }, WV0);   // even phase: read {0,1}
    PHNM(2, 3, { TRIO_N(s0 + 4); TRIO_N(s0 + 5); }, WV0);   // odd phase: read {2,3}
  }
  // phase P-2 (even): stage last pair; phase P-1: tail
  PHNM(0, 1, { TRIO_N(L - 2); TRIO_N(L - 1); }, WV0);
  PHNM_LAST(2, 3);

  const int rbase = 4 * ls;
  float bsv[2];
#pragma unroll
  for (int nt = 0; nt < 2; nt++) bsv[nt] = bias[n0 + wn * 64 + nt * 32 + l31];
#pragma unroll
  for (int mt = 0; mt < 2; mt++)
#pragma unroll
    for (int nt = 0; nt < 2; nt++)
#pragma unroll
      for (int reg = 0; reg < 16; reg++) {
        const size_t row = (size_t)(m0 + wm * 64 + mt * 32 + rbase + (reg & 3) + 8 * (reg >> 2));
        const int col = n0 + wn * 64 + nt * 32 + l31;
        float v = acc[mt][nt][reg] + bsv[nt];
        if (flags & 1) v = gelu_f(v);
        if (flags & 2) v += res[row * N + col];
        if (flags & 4) ((unsigned short*)C)[row * N + col] = f2bf(v);
        else ((float*)C)[row * N + col] = v;
      }
}

// ---------- Hebbian phase A: per-chunk decayed outer-product sums ----------
__global__ __launch_bounds__(256) void k_heb_chunk(
    const unsigned short* __restrict__ qkv, const float* __restrict__ gam,
    float* __restrict__ U, float* __restrict__ Dc) {
  __shared__ float kw[4096];
  __shared__ float vS[4096];
  __shared__ float cum[64];
  const int bx = blockIdx.x;
  const int c = bx & 31, bh = bx >> 5, b = bh >> 3, h = bh & 7;
  const int t = threadIdx.x;
  const int n0 = c * 64;
  const size_t base = ((size_t)(b * Nn_ + n0)) * 1536 + h * 64;
#pragma unroll
  for (int l = 0; l < 2; l++) {
    const int idx8 = t + 256 * l;
    const int s = idx8 >> 3;
    const int d0 = (idx8 & 7) << 3;
    const size_t gi = base + (size_t)s * 1536 + d0;
    bf8_to_f(qkv + gi + 512, &kw[s * 64 + d0]);
    bf8_to_f(qkv + gi + 1024, &vS[s * 64 + d0]);
  }
  if (t < 64) {
    float val = 0.01f * gam[b * Nn_ + n0 + t];
#pragma unroll
    for (int off = 1; off < 64; off <<= 1) {
      const float o = __shfl_up(val, off, 64);
      if (t >= off) val += o;
    }
    cum[t] = val;
  }
  __syncthreads();
  const float total = cum[63];
#pragma unroll
  for (int l = 0; l < 16; l++) {
    const int idx = t + 256 * l;
    const int s = idx >> 6;
    kw[idx] *= 0.1f * __expf(cum[s] - total);
  }
  __syncthreads();
  const int td = (t & 15) << 2, te = (t >> 4) << 2;
  float acc[4][4];
#pragma unroll
  for (int i = 0; i < 4; i++)
#pragma unroll
    for (int j = 0; j < 4; j++) acc[i][j] = 0.0f;
  for (int s = 0; s < 64; s++) {
    const float4 kk = *(const float4*)&kw[s * 64 + td];
    const float4 vv = *(const float4*)&vS[s * 64 + te];
    const float ka[4] = {kk.x, kk.y, kk.z, kk.w};
    const float va[4] = {vv.x, vv.y, vv.z, vv.w};
#pragma unroll
    for (int i = 0; i < 4; i++)
#pragma unroll
      for (int j = 0; j < 4; j++) acc[i][j] = fmaf(ka[i], va[j], acc[i][j]);
  }
  float* Up = U + (size_t)bx * 4096;
#pragma unroll
  for (int i = 0; i < 4; i++)
#pragma unroll
    for (int j = 0; j < 4; j++) Up[(td + i) * 64 + te + j] = acc[i][j];
  if (t == 0) Dc[bx] = __expf(-total);
}

// ---------- Hebbian phase B: carry W across chunks (one thread per element) ----------
__global__ __launch_bounds__(256) void k_heb_scan(
    const float* __restrict__ U, const float* __restrict__ Dc, float* __restrict__ Win) {
  const int gid = blockIdx.x * 256 + threadIdx.x;   // 0..131071
  const int bh = gid >> 12, el = gid & 4095;
  float w = 0.0f;
#pragma unroll 4
  for (int c = 0; c < 32; c++) {
    const size_t idx = (((size_t)(bh * 32 + c)) << 12) + el;
    Win[idx] = w;
    w = Dc[bh * 32 + c] * w + U[idx];
  }
}

// ---------- Hebbian phase C: intra-chunk causal + inter-chunk q@W_in ----------
__global__ __launch_bounds__(256) void k_heb_out(
    const unsigned short* __restrict__ qkv, const float* __restrict__ gam,
    const float* __restrict__ Win, unsigned short* __restrict__ heb) {
  __shared__ float qS[4096];
  __shared__ float kT[4096];
  __shared__ float vS[4096];
  __shared__ float P[4096];
  const int bx = blockIdx.x;
  const int c = bx & 31, bh = bx >> 5, b = bh >> 3, h = bh & 7;
  const int t = threadIdx.x;
  const int n0 = c * 64;
  const size_t base = ((size_t)(b * Nn_ + n0)) * 1536 + h * 64;
#pragma unroll
  for (int l = 0; l < 2; l++) {
    const int idx8 = t + 256 * l;
    const int s = idx8 >> 3;
    const int d0 = (idx8 & 7) << 3;
    const size_t gi = base + (size_t)s * 1536 + d0;
    bf8_to_f(qkv + gi, &qS[s * 64 + d0]);
    bf8_to_f(qkv + gi + 1024, &vS[s * 64 + d0]);
    float tmp[8];
    bf8_to_f(qkv + gi + 512, tmp);
#pragma unroll
    for (int j = 0; j < 8; j++) kT[(d0 + j) * 64 + s] = tmp[j];
  }
  if (t < 64) {
    float val = 0.01f * gam[b * Nn_ + n0 + t];
#pragma unroll
    for (int off = 1; off < 64; off <<= 1) {
      const float o = __shfl_up(val, off, 64);
      if (t >= off) val += o;
    }
    P[t] = val;
  }
  __syncthreads();
  const int tr = (t >> 4) << 2;
  const int tc = (t & 15) << 2;
  float er[4], es[4];
#pragma unroll
  for (int r = 0; r < 4; r++) er[r] = __expf(-P[tr + r]);
#pragma unroll
  for (int j = 0; j < 4; j++) es[j] = 0.1f * __expf(P[tc + j]);
  __syncthreads();
  float acc[4][4];
#pragma unroll
  for (int i = 0; i < 4; i++)
#pragma unroll
    for (int j = 0; j < 4; j++) acc[i][j] = 0.0f;
  for (int d = 0; d < 64; d++) {
    const float4 kk = *(const float4*)&kT[d * 64 + tc];
    const float ka[4] = {kk.x, kk.y, kk.z, kk.w};
#pragma unroll
    for (int r = 0; r < 4; r++) {
      const float qv = qS[(tr + r) * 64 + d];
#pragma unroll
      for (int j = 0; j < 4; j++) acc[r][j] = fmaf(qv, ka[j], acc[r][j]);
    }
  }
#pragma unroll
  for (int r = 0; r < 4; r++)
#pragma unroll
    for (int j = 0; j < 4; j++) {
      const int tt = tr + r, ssi = tc + j;
      const float wgt = (ssi <= tt) ? er[r] * es[j] : 0.0f;
      P[tt * 64 + ssi] = acc[r][j] * wgt;
    }
  __syncthreads();
  const size_t wb = (size_t)bx * 4096;
#pragma unroll
  for (int l = 0; l < 16; l++) {
    const int idx = t + 256 * l;
    kT[idx] = Win[wb + idx];
  }
  __syncthreads();
  float o1[4][4], o2[4][4];
#pragma unroll
  for (int i = 0; i < 4; i++)
#pragma unroll
    for (int j = 0; j < 4; j++) { o1[i][j] = 0.0f; o2[i][j] = 0.0f; }
  for (int s = 0; s < 64; s++) {
    const float4 vv = *(const float4*)&vS[s * 64 + tc];
    const float4 ww = *(const float4*)&kT[s * 64 + tc];
    const float va[4] = {vv.x, vv.y, vv.z, vv.w};
    const float wa[4] = {ww.x, ww.y, ww.z, ww.w};
#pragma unroll
    for (int r = 0; r < 4; r++) {
      const float pv = P[(tr + r) * 64 + s];
      const float qv = qS[(tr + r) * 64 + s];
#pragma unroll
      for (int j = 0; j < 4; j++) {
        o1[r][j] = fmaf(pv, va[j], o1[r][j]);
        o2[r][j] = fmaf(qv, wa[j], o2[r][j]);
      }
    }
  }
#pragma unroll
  for (int r = 0; r < 4; r++) {
    const int n = n0 + tr + r;
    ushort4 pk;
    pk.x = f2bf(o1[r][0] + er[r] * o2[r][0]);
    pk.y = f2bf(o1[r][1] + er[r] * o2[r][1]);
    pk.z = f2bf(o1[r][2] + er[r] * o2[r][2]);
    pk.w = f2bf(o1[r][3] + er[r] * o2[r][3]);
    *(ushort4*)&heb[((size_t)b * Nn_ + n) * 512 + h * 64 + tc] = pk;
  }
}

extern "C" void kernel_launch(void* const* d_in, const int* in_sizes, int n_in,
                              void* d_out, int out_size, void* d_ws, size_t ws_size,
                              hipStream_t stream) {
  const float* x     = (const float*)d_in[0];
  const float* ln1g  = (const float*)d_in[1];
  const float* ln1b  = (const float*)d_in[2];
  const float* ln2g  = (const float*)d_in[3];
  const float* ln2b  = (const float*)d_in[4];
  const float* ln3g  = (const float*)d_in[5];
  const float* ln3b  = (const float*)d_in[6];
  const float* w_pot = (const float*)d_in[7];
  const float* b_pot = (const float*)d_in[8];
  const float* w_bk  = (const float*)d_in[9];
  const float* b_bk  = (const float*)d_in[10];
  const float* w_qkv = (const float*)d_in[11];
  const float* b_qkv = (const float*)d_in[12];
  const float* w_out = (const float*)d_in[13];
  const float* b_out = (const float*)d_in[14];
  const float* w_ff1 = (const float*)d_in[15];
  const float* b_ff1 = (const float*)d_in[16];
  const float* w_ff2 = (const float*)d_in[17];
  const float* b_ff2 = (const float*)d_in[18];
  float* out = (float*)d_out;
  float* ws = (float*)d_ws;

  // ---- workspace layout (float units), total 34,668,544 floats = 138.7 MB ----
  float* V   = ws;
  float* gam = V + 8192;
  float* aRe = gam + 8192;
  float* aIm = aRe + 8192;
  float* bRe = aIm + 8192;
  float* bIm = bRe + 8192;
  float* Dc  = bIm + 8192;
  float* HID = ws + 65536;             // 16.78M f32 (67.1MB): x1 + qkv early; ff hidden late
  float* x1   = HID;                   // 8.39M f32
  unsigned short* qkvb = (unsigned short*)(HID + 8388608);  // 12.58M shorts
  unsigned short* hid  = (unsigned short*)HID;              // 8192x4096 bf16 (ff phase)
  float* RC   = HID + 16777216;        // 8.39M f32: U+Win, later x2
  float* U    = RC;
  float* Win  = RC + 4194304;
  float* x2   = RC;
  float* RD   = RC + 8388608;          // 4.19M f32: xn2/heb/xn3 (bf16)
  unsigned short* xnb = (unsigned short*)RD;
  unsigned short* heb = (unsigned short*)RD;
  unsigned short* wE  = (unsigned short*)(RD + 4194304);
  unsigned short* wqkvT = wE;                    // 1536x1024
  unsigned short* woutT = wqkvT + 1572864;       // 1024x512
  unsigned short* wff1T = woutT + 524288;        // 4096x1024
  unsigned short* wff2T = wff1T + 4194304;       // 1024x4096

  // weight transposes (fp32 KxN -> bf16 NxK)
  k_wt<<<dim3(1536 / 32, 1024 / 32), 256, 0, stream>>>(w_qkv, wqkvT, 1024, 1536);
  k_wt<<<dim3(1024 / 32, 512 / 32), 256, 0, stream>>>(w_out, woutT, 512, 1024);
  k_wt<<<dim3(4096 / 32, 1024 / 32), 256, 0, stream>>>(w_ff1, wff1T, 1024, 4096);
  k_wt<<<dim3(1024 / 32, 4096 / 32), 256, 0, stream>>>(w_ff2, wff2T, 4096, 1024);

  k_ln_pot<<<Tt, 256, 0, stream>>>(x, ln1g, ln1b, w_pot, b_pot, V, gam);
  k_cf_par<<<8, 64, 0, stream>>>(V, gam, aRe, aIm, bRe, bIm);
  k_bk_add<<<Tt, 256, 0, stream>>>(x, aRe, aIm, bRe, bIm, V, gam, w_bk, b_bk, x1);
  k_ln_bf<<<Tt, 256, 0, stream>>>(x1, ln2g, ln2b, xnb);
  // qkv: (8192x1024)@(1024x1536) -> bf16   [256^2 tile, nb=6, 192 blocks]
  k_gemm8<<<192, 512, 0, stream>>>(xnb, wqkvT, b_qkv, nullptr, qkvb,
                                   8192, 1024, 1536, 4, 6);
  k_heb_chunk<<<1024, 256, 0, stream>>>(qkvb, gam, U, Dc);
  k_heb_scan<<<512, 256, 0, stream>>>(U, Dc, Win);
  k_heb_out<<<1024, 256, 0, stream>>>(qkvb, gam, Win, heb);
  // out-proj: (8192x512)@(512x1024) + x1 -> f32 x2   [128x256 tile, nb=4, 256 blocks]
  k_gemm8n<<<256, 512, 0, stream>>>(heb, woutT, b_out, x1, x2,
                                    8192, 512, 1024, 2, 4);
  k_ln_bf<<<Tt, 256, 0, stream>>>(x2, ln3g, ln3b, xnb);
  // ff1: (8192x1024)@(1024x4096) gelu -> bf16 hid   [256^2 tile, nb=16, 512 blocks]
  k_gemm8<<<512, 512, 0, stream>>>(xnb, wff1T, b_ff1, nullptr, hid,
                                   8192, 1024, 4096, 1 | 4, 16);
  // ff2: (8192x4096)@(4096x1024) + x2 -> f32 out   [128x256 tile, nb=4, 256 blocks]
  k_gemm8n<<<256, 512, 0, stream>>>(hid, wff2T, b_ff2, x2, out,
                                    8192, 4096, 1024, 2, 4);
}